// Round 6
// baseline (2401.602 us; speedup 1.0000x reference)
//
#include <hip/hip_runtime.h>
#include <hip/hip_bf16.h>
#include <cstdint>

#define NTOK 16384
#define CDIM 512
#define KNB 32
#define CPD 128
#define NH 8
#define SD 64
#define QKV_W 1536   // H*3*S
#define DCAT 1536    // H*CP + H*S

typedef __attribute__((ext_vector_type(8))) short short8;
typedef __attribute__((ext_vector_type(4))) float f32x4;

__device__ inline float bl16(unsigned w) { return __uint_as_float(w << 16); }
__device__ inline float bh16(unsigned w) { return __uint_as_float(w & 0xffff0000u); }

__device__ inline ushort bf2u(float x) {
    __hip_bfloat16 b = __float2bfloat16(x);
    return *(const ushort*)&b;
}

__device__ inline void gload_lds16(const void* g, void* l) {
    __builtin_amdgcn_global_load_lds((const __attribute__((address_space(1))) void*)g,
                                     (__attribute__((address_space(3))) void*)l, 16, 0, 0);
}

// ---------------- elementwise fp32 -> bf16 convert (vectorized) ----------------
__global__ __launch_bounds__(256) void cvt_bf16_kernel(const float4* __restrict__ in,
                                                       ushort4* __restrict__ out, int n4)
{
    const int idx = blockIdx.x * 256 + threadIdx.x;
    if (idx < n4) {
        const float4 v = in[idx];
        ushort4 o;
        o.x = bf2u(v.x); o.y = bf2u(v.y); o.z = bf2u(v.z); o.w = bf2u(v.w);
        out[idx] = o;
    }
}

// ---------------- transpose + convert: in [R][Cc] fp32 -> out [Cc][R] bf16 ----------------
__global__ __launch_bounds__(256) void transpose_cvt(const float* __restrict__ in,
                                                     __hip_bfloat16* __restrict__ out,
                                                     int R, int Cc)
{
    __shared__ float t[32][33];
    const int c0 = blockIdx.x * 32, r0 = blockIdx.y * 32;
    const int tx = threadIdx.x & 31, ty = threadIdx.x >> 5;
    #pragma unroll
    for (int rr = ty; rr < 32; rr += 8)
        t[rr][tx] = in[(size_t)(r0 + rr) * Cc + c0 + tx];
    __syncthreads();
    #pragma unroll
    for (int rr = ty; rr < 32; rr += 8)
        out[(size_t)(c0 + rr) * R + r0 + tx] = __float2bfloat16(t[tx][rr]);
}

// ---------------- bf16 MFMA GEMM: C[M,N] = A[M,K](bf16) @ Bt[N,K](bf16)^T (+bias) -------
template<bool ADD_BIAS>
__global__ __launch_bounds__(256) void gemm_bf16(const ushort* __restrict__ A,
                                                 const ushort* __restrict__ Bt,
                                                 const float* __restrict__ bias,
                                                 float* __restrict__ C,
                                                 int M, int N, int K)
{
    __shared__ __align__(16) ushort Asl[128 * 32];
    __shared__ __align__(16) ushort Bsl[128 * 32];

    const int tid = threadIdx.x;
    const int wave = tid >> 6;
    const int lane = tid & 63;
    const int m0 = blockIdx.y * 128;
    const int n0 = blockIdx.x * 128;
    const int wr = wave >> 1, wc = wave & 1;

    f32x4 acc[4][4] = {};

    const int st_row_in_chunk = lane >> 2;
    const int st_bcol = (lane & 3) * 16;

    const int lr = lane & 15;
    const int kg = lane >> 4;

    for (int kt = 0; kt < K; kt += 32) {
        #pragma unroll
        for (int p = 0; p < 2; ++p) {
            const int chunk = wave * 2 + p;
            const int row = chunk * 16 + st_row_in_chunk;
            const char* asrc = (const char*)(A + (size_t)(m0 + row) * K + kt) + st_bcol;
            const char* bsrc = (const char*)(Bt + (size_t)(n0 + row) * K + kt) + st_bcol;
            gload_lds16(asrc, (char*)Asl + chunk * 1024);
            gload_lds16(bsrc, (char*)Bsl + chunk * 1024);
        }
        __syncthreads();

        short8 a[4], b[4];
        #pragma unroll
        for (int m = 0; m < 4; ++m)
            a[m] = *(const short8*)&Asl[(wr * 64 + m * 16 + lr) * 32 + kg * 8];
        #pragma unroll
        for (int n = 0; n < 4; ++n)
            b[n] = *(const short8*)&Bsl[(wc * 64 + n * 16 + lr) * 32 + kg * 8];
        #pragma unroll
        for (int m = 0; m < 4; ++m)
            #pragma unroll
            for (int n = 0; n < 4; ++n)
                acc[m][n] = __builtin_amdgcn_mfma_f32_16x16x32_bf16(a[m], b[n], acc[m][n], 0, 0, 0);
        __syncthreads();
    }

    #pragma unroll
    for (int m = 0; m < 4; ++m) {
        #pragma unroll
        for (int n = 0; n < 4; ++n) {
            const int col = n0 + wc * 64 + n * 16 + lr;
            const float bv = ADD_BIAS ? bias[col] : 0.0f;
            #pragma unroll
            for (int r = 0; r < 4; ++r) {
                const int row = m0 + wr * 64 + m * 16 + kg * 4 + r;
                C[(size_t)row * N + col] = acc[m][n][r] + bv;
            }
        }
    }
}

// ---------------- LayerNorm q,k + compact bf16 q/k/v: one wave per (i,h) -------------
__global__ __launch_bounds__(256) void ln_kernel(const float* __restrict__ qkv,
                                                 const float* __restrict__ g_q,
                                                 const float* __restrict__ b_q,
                                                 const float* __restrict__ g_k,
                                                 const float* __restrict__ b_k,
                                                 __hip_bfloat16* __restrict__ qc,
                                                 __hip_bfloat16* __restrict__ kc,
                                                 __hip_bfloat16* __restrict__ vc)
{
    const int gid = blockIdx.x * 4 + (threadIdx.x >> 6);   // i*8 + h
    const int lane = threadIdx.x & 63;

    const float* p = qkv + (size_t)(gid >> 3) * QKV_W + (gid & 7) * 192;
    const float q = p[lane];
    const float k = p[64 + lane];
    const float v = p[128 + lane];

    float sq = q, sk = k;
    #pragma unroll
    for (int o = 1; o < 64; o <<= 1) { sq += __shfl_xor(sq, o); sk += __shfl_xor(sk, o); }
    const float mq = sq * (1.0f / 64.0f), mk = sk * (1.0f / 64.0f);
    const float dq = q - mq, dk = k - mk;
    float vq = dq * dq, vk = dk * dk;
    #pragma unroll
    for (int o = 1; o < 64; o <<= 1) { vq += __shfl_xor(vq, o); vk += __shfl_xor(vk, o); }
    const float iq = rsqrtf(vq * (1.0f / 64.0f) + 1e-5f);
    const float ik = rsqrtf(vk * (1.0f / 64.0f) + 1e-5f);

    const size_t o64 = (size_t)gid * 64 + lane;
    qc[o64] = __float2bfloat16(dq * iq * g_q[lane] + b_q[lane]);
    kc[o64] = __float2bfloat16(dk * ik * g_k[lane] + b_k[lane]);
    vc[o64] = __float2bfloat16(v);
}

// ---------------- fused neighbour attention: one block per token i ----------------
__global__ __launch_bounds__(256, 8) void attn_kernel(const __hip_bfloat16* __restrict__ qc,
                                                      const __hip_bfloat16* __restrict__ kc,
                                                      const __hip_bfloat16* __restrict__ vc,
                                                      const float* __restrict__ pair,
                                                      const int* __restrict__ nbr,
                                                      const float* __restrict__ w_bias,
                                                      __hip_bfloat16* __restrict__ cat)
{
    __shared__ __align__(16) ushort s_pairb[KNB][CPD + 8];  // 8.5 KB, row stride 272 B
    __shared__ __align__(16) ushort s_wbTb[NH][CPD + 8];    // 2.2 KB
    __shared__ __align__(16) ushort s_qb[NH][SD + 8];       // 1.2 KB
    __shared__ __align__(16) float s_att[NH][KNB + 4];      // logits, transposed
    __shared__ __align__(16) float s_att2[NH][KNB + 4];     // weights, transposed
    __shared__ int s_nb[KNB];

    const int i = blockIdx.x;
    const int tid = threadIdx.x;

    const int j = tid >> 3;
    const int h = tid & 7;

    // --- k-gather first half pre-barrier (latency hides under staging)
    const int rowj = nbr[i * KNB + j];
    const int rk = rowj < 0 ? 0 : rowj;
    const uint4* kp = (const uint4*)(kc + ((size_t)rk * NH + h) * SD);
    uint4 ka0 = kp[0], ka1 = kp[1], ka2 = kp[2], ka3 = kp[3];

    // --- LDS staging
    if (tid < KNB) s_nb[tid] = nbr[i * KNB + tid];
    if (tid < 64) {   // q already bf16: straight uint4 copy
        const uint4 qw = ((const uint4*)(qc + (size_t)i * 512))[tid];
        *(uint4*)&s_qb[tid >> 3][(tid & 7) * 8] = qw;
    }
    {   // w_bias [128][8] fp32 -> s_wbTb[h][c] bf16
        const float4 w4 = ((const float4*)w_bias)[tid];
        const int c = tid >> 1;
        const int h0 = (tid & 1) * 4;
        s_wbTb[h0 + 0][c] = bf2u(w4.x);
        s_wbTb[h0 + 1][c] = bf2u(w4.y);
        s_wbTb[h0 + 2][c] = bf2u(w4.z);
        s_wbTb[h0 + 3][c] = bf2u(w4.w);
    }
    {   // pair tile fp32 -> bf16 LDS
        const float4* pr = (const float4*)(pair + (size_t)i * KNB * CPD);
        #pragma unroll
        for (int t2 = 0; t2 < 2; ++t2) {
            const int ch = t2 * 256 + tid;
            const int row = ch >> 4;
            const int c8 = (ch & 15) * 8;
            const float4 a = pr[row * 32 + (c8 >> 2)];
            const float4 b = pr[row * 32 + (c8 >> 2) + 1];
            short8 o;
            o[0] = (short)bf2u(a.x); o[1] = (short)bf2u(a.y);
            o[2] = (short)bf2u(a.z); o[3] = (short)bf2u(a.w);
            o[4] = (short)bf2u(b.x); o[5] = (short)bf2u(b.y);
            o[6] = (short)bf2u(b.z); o[7] = (short)bf2u(b.w);
            *(short8*)&s_pairb[row][c8] = o;
        }
    }
    __syncthreads();

    // --- issue k second half; latency hidden under dot part 1
    uint4 kb0 = kp[4], kb1 = kp[5], kb2 = kp[6], kb3 = kp[7];

    // --- dot: consume all k registers now (frees them before bias)
    const uint4* qrow = (const uint4*)&s_qb[h][0];
    float d0 = 0.f, d1 = 0.f, d2 = 0.f, d3 = 0.f;
    #pragma unroll
    for (int u = 0; u < 4; ++u) {
        uint4 K;
        switch (u) { case 0: K = ka0; break; case 1: K = ka1; break;
                     case 2: K = ka2; break; default: K = ka3; break; }
        const uint4 Q = qrow[u];
        d0 = fmaf(bl16(K.x), bl16(Q.x), fmaf(bh16(K.x), bh16(Q.x), d0));
        d1 = fmaf(bl16(K.y), bl16(Q.y), fmaf(bh16(K.y), bh16(Q.y), d1));
        d2 = fmaf(bl16(K.z), bl16(Q.z), fmaf(bh16(K.z), bh16(Q.z), d2));
        d3 = fmaf(bl16(K.w), bl16(Q.w), fmaf(bh16(K.w), bh16(Q.w), d3));
    }
    #pragma unroll
    for (int u = 0; u < 4; ++u) {
        uint4 K;
        switch (u) { case 0: K = kb0; break; case 1: K = kb1; break;
                     case 2: K = kb2; break; default: K = kb3; break; }
        const uint4 Q = qrow[u + 4];
        d0 = fmaf(bl16(K.x), bl16(Q.x), fmaf(bh16(K.x), bh16(Q.x), d0));
        d1 = fmaf(bl16(K.y), bl16(Q.y), fmaf(bh16(K.y), bh16(Q.y), d1));
        d2 = fmaf(bl16(K.z), bl16(Q.z), fmaf(bh16(K.z), bh16(Q.z), d2));
        d3 = fmaf(bl16(K.w), bl16(Q.w), fmaf(bh16(K.w), bh16(Q.w), d3));
    }

    // --- bias[j,h]: bf16 LDS reads, 4 accumulators
    float b0 = 0.f, b1 = 0.f, b2 = 0.f, b3 = 0.f;
    {
        const uint4* prow = (const uint4*)&s_pairb[j][0];
        const uint4* wrow = (const uint4*)&s_wbTb[h][0];
        #pragma unroll
        for (int u = 0; u < 16; ++u) {
            const uint4 P = prow[u];
            const uint4 W = wrow[u];
            b0 = fmaf(bl16(P.x), bl16(W.x), fmaf(bh16(P.x), bh16(W.x), b0));
            b1 = fmaf(bl16(P.y), bl16(W.y), fmaf(bh16(P.y), bh16(W.y), b1));
            b2 = fmaf(bl16(P.z), bl16(W.z), fmaf(bh16(P.z), bh16(W.z), b2));
            b3 = fmaf(bl16(P.w), bl16(W.w), fmaf(bh16(P.w), bh16(W.w), b3));
        }
    }
    const float biasv = (b0 + b1) + (b2 + b3);

    float logit = -1e9f;
    if (rowj >= 0) {
        const float dot = (d0 + d1) + (d2 + d3);
        logit = 0.70710678118f * (dot * 0.125f + biasv);
    }
    s_att[h][j] = logit;
    __syncthreads();

    // --- softmax over j: read own h-column as 8 float4 into regs, reduce in-register
    {
        float lv[32];
        #pragma unroll
        for (int t = 0; t < 8; ++t) {
            const float4 w = *(const float4*)&s_att[h][t * 4];
            lv[t * 4 + 0] = w.x; lv[t * 4 + 1] = w.y;
            lv[t * 4 + 2] = w.z; lv[t * 4 + 3] = w.w;
        }
        float m0 = lv[0], m1 = lv[1];
        #pragma unroll
        for (int t = 2; t < 32; t += 2) { m0 = fmaxf(m0, lv[t]); m1 = fmaxf(m1, lv[t + 1]); }
        const float mx = fmaxf(m0, m1);
        float s0 = 0.f, s1 = 0.f;
        #pragma unroll
        for (int t = 0; t < 32; t += 2) {
            s0 += __expf(lv[t] - mx);
            s1 += __expf(lv[t + 1] - mx);
        }
        float aval = __expf(logit - mx) / (s0 + s1);
        if (rowj < 0) aval = 0.0f;
        s_att2[h][j] = aval;
    }
    __syncthreads();

    // --- out_pair[h,c] -> cat[i, h*128+c]; att via float4 reads, pair b64, 4 chunks
    {
        const int h2 = tid >> 5;
        const int c0 = (tid & 31) * 4;
        float4 aA = make_float4(0.f, 0.f, 0.f, 0.f);
        float4 aB = make_float4(0.f, 0.f, 0.f, 0.f);
        #pragma unroll
        for (int t = 0; t < 4; ++t) {
            const float4 w0 = *(const float4*)&s_att2[h2][t * 8];
            const float4 w1 = *(const float4*)&s_att2[h2][t * 8 + 4];
            const float av[8] = {w0.x, w0.y, w0.z, w0.w, w1.x, w1.y, w1.z, w1.w};
            #pragma unroll
            for (int u = 0; u < 8; u += 2) {
                const int jj = t * 8 + u;
                const uint2 p0 = *(const uint2*)&s_pairb[jj][c0];
                const uint2 p1 = *(const uint2*)&s_pairb[jj + 1][c0];
                const float a0 = av[u], a1 = av[u + 1];
                aA.x = fmaf(a0, bl16(p0.x), aA.x); aA.y = fmaf(a0, bh16(p0.x), aA.y);
                aA.z = fmaf(a0, bl16(p0.y), aA.z); aA.w = fmaf(a0, bh16(p0.y), aA.w);
                aB.x = fmaf(a1, bl16(p1.x), aB.x); aB.y = fmaf(a1, bh16(p1.x), aB.y);
                aB.z = fmaf(a1, bl16(p1.y), aB.z); aB.w = fmaf(a1, bh16(p1.y), aB.w);
            }
        }
        ushort4 o;
        o.x = bf2u(aA.x + aB.x); o.y = bf2u(aA.y + aB.y);
        o.z = bf2u(aA.z + aB.z); o.w = bf2u(aA.w + aB.w);
        *(ushort4*)&cat[(size_t)i * DCAT + h2 * CPD + c0] = o;
    }

    // --- out_scalar: 4 phases of {load 2 v rows, fma}; att from 2 float4 reads
    {
        const int wv = tid >> 6;
        const int lane = tid & 63;
        const int slot = wv * 16 + (lane & 15);   // h = slot>>3, 16B chunk = slot&7
        const int jg = lane >> 4;                 // rows jg*8 .. jg*8+7
        const int hh = slot >> 3;

        const float4 w0 = *(const float4*)&s_att2[hh][jg * 8];
        const float4 w1 = *(const float4*)&s_att2[hh][jg * 8 + 4];
        const float av[8] = {w0.x, w0.y, w0.z, w0.w, w1.x, w1.y, w1.z, w1.w};

        float acc0 = 0.f, acc1 = 0.f, acc2 = 0.f, acc3 = 0.f;
        float acc4 = 0.f, acc5 = 0.f, acc6 = 0.f, acc7 = 0.f;
        const char* vbase = (const char*)vc;
        #pragma unroll
        for (int u2 = 0; u2 < 4; ++u2) {
            const int j0 = jg * 8 + u2 * 2;
            const int r0 = s_nb[j0] < 0 ? 0 : s_nb[j0];
            const int r1 = s_nb[j0 + 1] < 0 ? 0 : s_nb[j0 + 1];
            const uint4 x0 = *(const uint4*)(vbase + (size_t)r0 * 1024 + slot * 16);
            const uint4 x1 = *(const uint4*)(vbase + (size_t)r1 * 1024 + slot * 16);
            const float a0 = av[u2 * 2], a1 = av[u2 * 2 + 1];
            acc0 = fmaf(a0, bl16(x0.x), acc0); acc1 = fmaf(a0, bh16(x0.x), acc1);
            acc2 = fmaf(a0, bl16(x0.y), acc2); acc3 = fmaf(a0, bh16(x0.y), acc3);
            acc4 = fmaf(a0, bl16(x0.z), acc4); acc5 = fmaf(a0, bh16(x0.z), acc5);
            acc6 = fmaf(a0, bl16(x0.w), acc6); acc7 = fmaf(a0, bh16(x0.w), acc7);
            acc0 = fmaf(a1, bl16(x1.x), acc0); acc1 = fmaf(a1, bh16(x1.x), acc1);
            acc2 = fmaf(a1, bl16(x1.y), acc2); acc3 = fmaf(a1, bh16(x1.y), acc3);
            acc4 = fmaf(a1, bl16(x1.z), acc4); acc5 = fmaf(a1, bh16(x1.z), acc5);
            acc6 = fmaf(a1, bl16(x1.w), acc6); acc7 = fmaf(a1, bh16(x1.w), acc7);
        }
        acc0 += __shfl_xor(acc0, 16); acc0 += __shfl_xor(acc0, 32);
        acc1 += __shfl_xor(acc1, 16); acc1 += __shfl_xor(acc1, 32);
        acc2 += __shfl_xor(acc2, 16); acc2 += __shfl_xor(acc2, 32);
        acc3 += __shfl_xor(acc3, 16); acc3 += __shfl_xor(acc3, 32);
        acc4 += __shfl_xor(acc4, 16); acc4 += __shfl_xor(acc4, 32);
        acc5 += __shfl_xor(acc5, 16); acc5 += __shfl_xor(acc5, 32);
        acc6 += __shfl_xor(acc6, 16); acc6 += __shfl_xor(acc6, 32);
        acc7 += __shfl_xor(acc7, 16); acc7 += __shfl_xor(acc7, 32);
        if (jg == 0) {
            short8 o;
            o[0] = (short)bf2u(acc0); o[1] = (short)bf2u(acc1);
            o[2] = (short)bf2u(acc2); o[3] = (short)bf2u(acc3);
            o[4] = (short)bf2u(acc4); o[5] = (short)bf2u(acc5);
            o[6] = (short)bf2u(acc6); o[7] = (short)bf2u(acc7);
            char* dst = (char*)cat + ((size_t)i * DCAT + NH * CPD) * 2 + slot * 16;
            *(short8*)dst = o;
        }
    }
}

extern "C" void kernel_launch(void* const* d_in, const int* in_sizes, int n_in,
                              void* d_out, int out_size, void* d_ws, size_t ws_size,
                              hipStream_t stream)
{
    const float* local  = (const float*)d_in[0];
    const float* pair   = (const float*)d_in[1];
    const int*   nbr    = (const int*)d_in[2];
    const float* w_qkv  = (const float*)d_in[4];
    const float* g_q    = (const float*)d_in[5];
    const float* b_q    = (const float*)d_in[6];
    const float* g_k    = (const float*)d_in[7];
    const float* b_k    = (const float*)d_in[8];
    const float* w_bias = (const float*)d_in[9];
    const float* w_out  = (const float*)d_in[10];
    const float* b_out  = (const float*)d_in[11];
    float* out = (float*)d_out;

    char* base = (char*)d_ws;
    float*          qkv   = (float*)base;                          // [N,1536] fp32
    __hip_bfloat16* cat_b = (__hip_bfloat16*)base;                 // aliases qkv after LN
    ushort*         lc    = (ushort*)(base + 100663296u);
    __hip_bfloat16* wqkvT = (__hip_bfloat16*)(base + 117440512u);
    __hip_bfloat16* woutT = (__hip_bfloat16*)(base + 119013376u);
    __hip_bfloat16* qc    = (__hip_bfloat16*)(base + 120586240u);
    __hip_bfloat16* kc    = (__hip_bfloat16*)(base + 137363456u);
    __hip_bfloat16* vc    = (__hip_bfloat16*)(base + 154140672u);

    cvt_bf16_kernel<<<(NTOK * CDIM / 4 + 255) / 256, 256, 0, stream>>>(
        (const float4*)local, (ushort4*)lc, NTOK * CDIM / 4);
    transpose_cvt<<<dim3(QKV_W / 32, CDIM / 32), 256, 0, stream>>>(w_qkv, wqkvT, CDIM, QKV_W);
    transpose_cvt<<<dim3(CDIM / 32, DCAT / 32), 256, 0, stream>>>(w_out, woutT, DCAT, CDIM);

    hipLaunchKernelGGL((gemm_bf16<false>), dim3(QKV_W / 128, NTOK / 128), dim3(256), 0, stream,
                       lc, (const ushort*)wqkvT, nullptr, qkv, NTOK, QKV_W, CDIM);

    ln_kernel<<<NTOK * NH / 4, 256, 0, stream>>>(qkv, g_q, b_q, g_k, b_k, qc, kc, vc);

    attn_kernel<<<NTOK, 256, 0, stream>>>(qc, kc, vc, pair, nbr, w_bias, cat_b);

    hipLaunchKernelGGL((gemm_bf16<true>), dim3(CDIM / 128, NTOK / 128), dim3(256), 0, stream,
                       (const ushort*)cat_b, (const ushort*)woutT, b_out, out, NTOK, CDIM, DCAT);
}

// Round 7
// 928.368 us; speedup vs baseline: 2.5869x; 2.5869x over previous
//
#include <hip/hip_runtime.h>
#include <hip/hip_bf16.h>
#include <cstdint>

#define NTOK 16384
#define CDIM 512
#define KNB 32
#define CPD 128
#define NH 8
#define SD 64
#define QKV_W 1536   // H*3*S
#define DCAT 1536    // H*CP + H*S

typedef __attribute__((ext_vector_type(8))) short short8;
typedef __attribute__((ext_vector_type(4))) float f32x4;

__device__ inline float bl16(unsigned w) { return __uint_as_float(w << 16); }
__device__ inline float bh16(unsigned w) { return __uint_as_float(w & 0xffff0000u); }

__device__ inline ushort bf2u(float x) {
    __hip_bfloat16 b = __float2bfloat16(x);
    return *(const ushort*)&b;
}

__device__ inline void gload_lds16(const void* g, void* l) {
    __builtin_amdgcn_global_load_lds((const __attribute__((address_space(1))) void*)g,
                                     (__attribute__((address_space(3))) void*)l, 16, 0, 0);
}

// ---------------- elementwise fp32 -> bf16 convert (vectorized) ----------------
__global__ __launch_bounds__(256) void cvt_bf16_kernel(const float4* __restrict__ in,
                                                       ushort4* __restrict__ out, int n4)
{
    const int idx = blockIdx.x * 256 + threadIdx.x;
    if (idx < n4) {
        const float4 v = in[idx];
        ushort4 o;
        o.x = bf2u(v.x); o.y = bf2u(v.y); o.z = bf2u(v.z); o.w = bf2u(v.w);
        out[idx] = o;
    }
}

// ---------------- transpose + convert: in [R][Cc] fp32 -> out [Cc][R] bf16 ----------------
__global__ __launch_bounds__(256) void transpose_cvt(const float* __restrict__ in,
                                                     __hip_bfloat16* __restrict__ out,
                                                     int R, int Cc)
{
    __shared__ float t[32][33];
    const int c0 = blockIdx.x * 32, r0 = blockIdx.y * 32;
    const int tx = threadIdx.x & 31, ty = threadIdx.x >> 5;
    #pragma unroll
    for (int rr = ty; rr < 32; rr += 8)
        t[rr][tx] = in[(size_t)(r0 + rr) * Cc + c0 + tx];
    __syncthreads();
    #pragma unroll
    for (int rr = ty; rr < 32; rr += 8)
        out[(size_t)(c0 + rr) * R + r0 + tx] = __float2bfloat16(t[tx][rr]);
}

// ---------------- bf16 MFMA GEMM: C[M,N] = A[M,K](bf16) @ Bt[N,K](bf16)^T (+bias) -------
template<bool ADD_BIAS>
__global__ __launch_bounds__(256) void gemm_bf16(const ushort* __restrict__ A,
                                                 const ushort* __restrict__ Bt,
                                                 const float* __restrict__ bias,
                                                 float* __restrict__ C,
                                                 int M, int N, int K)
{
    __shared__ __align__(16) ushort Asl[128 * 32];
    __shared__ __align__(16) ushort Bsl[128 * 32];

    const int tid = threadIdx.x;
    const int wave = tid >> 6;
    const int lane = tid & 63;
    const int m0 = blockIdx.y * 128;
    const int n0 = blockIdx.x * 128;
    const int wr = wave >> 1, wc = wave & 1;

    f32x4 acc[4][4] = {};

    const int st_row_in_chunk = lane >> 2;
    const int st_bcol = (lane & 3) * 16;

    const int lr = lane & 15;
    const int kg = lane >> 4;

    for (int kt = 0; kt < K; kt += 32) {
        #pragma unroll
        for (int p = 0; p < 2; ++p) {
            const int chunk = wave * 2 + p;
            const int row = chunk * 16 + st_row_in_chunk;
            const char* asrc = (const char*)(A + (size_t)(m0 + row) * K + kt) + st_bcol;
            const char* bsrc = (const char*)(Bt + (size_t)(n0 + row) * K + kt) + st_bcol;
            gload_lds16(asrc, (char*)Asl + chunk * 1024);
            gload_lds16(bsrc, (char*)Bsl + chunk * 1024);
        }
        __syncthreads();

        short8 a[4], b[4];
        #pragma unroll
        for (int m = 0; m < 4; ++m)
            a[m] = *(const short8*)&Asl[(wr * 64 + m * 16 + lr) * 32 + kg * 8];
        #pragma unroll
        for (int n = 0; n < 4; ++n)
            b[n] = *(const short8*)&Bsl[(wc * 64 + n * 16 + lr) * 32 + kg * 8];
        #pragma unroll
        for (int m = 0; m < 4; ++m)
            #pragma unroll
            for (int n = 0; n < 4; ++n)
                acc[m][n] = __builtin_amdgcn_mfma_f32_16x16x32_bf16(a[m], b[n], acc[m][n], 0, 0, 0);
        __syncthreads();
    }

    #pragma unroll
    for (int m = 0; m < 4; ++m) {
        #pragma unroll
        for (int n = 0; n < 4; ++n) {
            const int col = n0 + wc * 64 + n * 16 + lr;
            const float bv = ADD_BIAS ? bias[col] : 0.0f;
            #pragma unroll
            for (int r = 0; r < 4; ++r) {
                const int row = m0 + wr * 64 + m * 16 + kg * 4 + r;
                C[(size_t)row * N + col] = acc[m][n][r] + bv;
            }
        }
    }
}

// ---------------- LayerNorm q,k + compact bf16 q/k/v: one wave per (i,h) -------------
__global__ __launch_bounds__(256) void ln_kernel(const float* __restrict__ qkv,
                                                 const float* __restrict__ g_q,
                                                 const float* __restrict__ b_q,
                                                 const float* __restrict__ g_k,
                                                 const float* __restrict__ b_k,
                                                 __hip_bfloat16* __restrict__ qc,
                                                 __hip_bfloat16* __restrict__ kc,
                                                 __hip_bfloat16* __restrict__ vc)
{
    const int gid = blockIdx.x * 4 + (threadIdx.x >> 6);   // i*8 + h
    const int lane = threadIdx.x & 63;

    const float* p = qkv + (size_t)(gid >> 3) * QKV_W + (gid & 7) * 192;
    const float q = p[lane];
    const float k = p[64 + lane];
    const float v = p[128 + lane];

    float sq = q, sk = k;
    #pragma unroll
    for (int o = 1; o < 64; o <<= 1) { sq += __shfl_xor(sq, o); sk += __shfl_xor(sk, o); }
    const float mq = sq * (1.0f / 64.0f), mk = sk * (1.0f / 64.0f);
    const float dq = q - mq, dk = k - mk;
    float vq = dq * dq, vk = dk * dk;
    #pragma unroll
    for (int o = 1; o < 64; o <<= 1) { vq += __shfl_xor(vq, o); vk += __shfl_xor(vk, o); }
    const float iq = rsqrtf(vq * (1.0f / 64.0f) + 1e-5f);
    const float ik = rsqrtf(vk * (1.0f / 64.0f) + 1e-5f);

    const size_t o64 = (size_t)gid * 64 + lane;
    qc[o64] = __float2bfloat16(dq * iq * g_q[lane] + b_q[lane]);
    kc[o64] = __float2bfloat16(dk * ik * g_k[lane] + b_k[lane]);
    vc[o64] = __float2bfloat16(v);
}

// ---------------- fused neighbour attention: one block per token i ----------------
__global__ __launch_bounds__(256, 6) void attn_kernel(const __hip_bfloat16* __restrict__ qc,
                                                      const __hip_bfloat16* __restrict__ kc,
                                                      const __hip_bfloat16* __restrict__ vc,
                                                      const float* __restrict__ pair,
                                                      const int* __restrict__ nbr,
                                                      const float* __restrict__ w_bias,
                                                      __hip_bfloat16* __restrict__ cat)
{
    __shared__ __align__(16) ushort s_pairb[KNB][CPD + 8];  // 8.5 KB, row 272 B
    __shared__ __align__(16) ushort s_wbTb[NH][CPD + 8];    // 2.2 KB
    __shared__ __align__(16) ushort s_qb[NH][SD + 8];       // 1.2 KB
    __shared__ __align__(16) float s_att[NH][KNB + 4];      // bias -> logits (in place)
    __shared__ __align__(16) float s_att2[NH][KNB + 4];     // softmax weights
    __shared__ int s_nb[KNB];

    const int i = blockIdx.x;
    const int tid = threadIdx.x;
    const int j = tid >> 3;
    const int h = tid & 7;
    const int wave = tid >> 6;
    const int lane = tid & 63;

    // --- k-gather first half pre-barrier (latency hides under staging)
    const int rowj = nbr[i * KNB + j];
    const int rk = rowj < 0 ? 0 : rowj;
    const uint4* kp = (const uint4*)(kc + ((size_t)rk * NH + h) * SD);
    uint4 ka0 = kp[0], ka1 = kp[1], ka2 = kp[2], ka3 = kp[3];

    // --- LDS staging
    if (tid < KNB) s_nb[tid] = nbr[i * KNB + tid];
    if (tid < 64) {   // q already bf16: straight uint4 copy
        const uint4 qw = ((const uint4*)(qc + (size_t)i * 512))[tid];
        *(uint4*)&s_qb[tid >> 3][(tid & 7) * 8] = qw;
    }
    {   // w_bias [128][8] fp32 -> s_wbTb[h][c] bf16
        const float4 w4 = ((const float4*)w_bias)[tid];
        const int c = tid >> 1;
        const int h0 = (tid & 1) * 4;
        s_wbTb[h0 + 0][c] = bf2u(w4.x);
        s_wbTb[h0 + 1][c] = bf2u(w4.y);
        s_wbTb[h0 + 2][c] = bf2u(w4.z);
        s_wbTb[h0 + 3][c] = bf2u(w4.w);
    }
    {   // pair tile fp32 -> bf16 LDS
        const float4* pr = (const float4*)(pair + (size_t)i * KNB * CPD);
        #pragma unroll
        for (int t2 = 0; t2 < 2; ++t2) {
            const int ch = t2 * 256 + tid;
            const int row = ch >> 4;
            const int c8 = (ch & 15) * 8;
            const float4 a = pr[row * 32 + (c8 >> 2)];
            const float4 b = pr[row * 32 + (c8 >> 2) + 1];
            short8 o;
            o[0] = (short)bf2u(a.x); o[1] = (short)bf2u(a.y);
            o[2] = (short)bf2u(a.z); o[3] = (short)bf2u(a.w);
            o[4] = (short)bf2u(b.x); o[5] = (short)bf2u(b.y);
            o[6] = (short)bf2u(b.z); o[7] = (short)bf2u(b.w);
            *(short8*)&s_pairb[row][c8] = o;
        }
    }
    __syncthreads();

    // --- issue k second half; latency hidden under MFMA/dot
    uint4 kb0 = kp[4], kb1 = kp[5], kb2 = kp[6], kb3 = kp[7];

    // --- waves 0,1: bias = P @ Wb via MFMA (tile = wave: rows j 0-15 / 16-31)
    if (wave < 2) {
        const int lr = lane & 15;
        const int kg = lane >> 4;
        f32x4 cacc = {};
        const ushort* arow = &s_pairb[wave * 16 + lr][kg * 8];
        const ushort* brow = &s_wbTb[lr & 7][kg * 8];   // cols n>=8 read garbage, discarded
        #pragma unroll
        for (int ks = 0; ks < 4; ++ks) {
            const short8 af = *(const short8*)(arow + ks * 32);
            const short8 bf = *(const short8*)(brow + ks * 32);
            cacc = __builtin_amdgcn_mfma_f32_16x16x32_bf16(af, bf, cacc, 0, 0, 0);
        }
        if (lr < 8) {   // C: col h = lr, row j = wave*16 + kg*4 + r
            const int jj = wave * 16 + kg * 4;
            s_att[lr][jj + 0] = cacc[0];
            s_att[lr][jj + 1] = cacc[1];
            s_att[lr][jj + 2] = cacc[2];
            s_att[lr][jj + 3] = cacc[3];
        }
    }

    // --- dot: all waves, consume ka then kb (registers freed before later phases)
    const uint4* qrow = (const uint4*)&s_qb[h][0];
    float d0 = 0.f, d1 = 0.f, d2 = 0.f, d3 = 0.f;
    #pragma unroll
    for (int u = 0; u < 4; ++u) {
        uint4 K;
        switch (u) { case 0: K = ka0; break; case 1: K = ka1; break;
                     case 2: K = ka2; break; default: K = ka3; break; }
        const uint4 Q = qrow[u];
        d0 = fmaf(bl16(K.x), bl16(Q.x), fmaf(bh16(K.x), bh16(Q.x), d0));
        d1 = fmaf(bl16(K.y), bl16(Q.y), fmaf(bh16(K.y), bh16(Q.y), d1));
        d2 = fmaf(bl16(K.z), bl16(Q.z), fmaf(bh16(K.z), bh16(Q.z), d2));
        d3 = fmaf(bl16(K.w), bl16(Q.w), fmaf(bh16(K.w), bh16(Q.w), d3));
    }
    #pragma unroll
    for (int u = 0; u < 4; ++u) {
        uint4 K;
        switch (u) { case 0: K = kb0; break; case 1: K = kb1; break;
                     case 2: K = kb2; break; default: K = kb3; break; }
        const uint4 Q = qrow[u + 4];
        d0 = fmaf(bl16(K.x), bl16(Q.x), fmaf(bh16(K.x), bh16(Q.x), d0));
        d1 = fmaf(bl16(K.y), bl16(Q.y), fmaf(bh16(K.y), bh16(Q.y), d1));
        d2 = fmaf(bl16(K.z), bl16(Q.z), fmaf(bh16(K.z), bh16(Q.z), d2));
        d3 = fmaf(bl16(K.w), bl16(Q.w), fmaf(bh16(K.w), bh16(Q.w), d3));
    }
    __syncthreads();   // bias in s_att ready

    // --- logit = w_L*(dot/8 + bias); in-place update of s_att[h][j]
    float logit = -1e9f;
    if (rowj >= 0) {
        const float dot = (d0 + d1) + (d2 + d3);
        logit = 0.70710678118f * (dot * 0.125f + s_att[h][j]);
    }
    s_att[h][j] = logit;
    __syncthreads();

    // --- out_scalar mapping + v-gather first half (latency hides under softmax)
    const int slot = wave * 16 + (lane & 15);   // h = slot>>3, 16B chunk = slot&7
    const int jg = lane >> 4;                   // owns rows jg*8 .. jg*8+7
    const int hh = slot >> 3;
    const char* vbase = (const char*)vc;
    uint4 va0, va1, va2, va3;
    {
        const int r0 = s_nb[jg * 8 + 0] < 0 ? 0 : s_nb[jg * 8 + 0];
        const int r1 = s_nb[jg * 8 + 1] < 0 ? 0 : s_nb[jg * 8 + 1];
        const int r2 = s_nb[jg * 8 + 2] < 0 ? 0 : s_nb[jg * 8 + 2];
        const int r3 = s_nb[jg * 8 + 3] < 0 ? 0 : s_nb[jg * 8 + 3];
        va0 = *(const uint4*)(vbase + (size_t)r0 * 1024 + slot * 16);
        va1 = *(const uint4*)(vbase + (size_t)r1 * 1024 + slot * 16);
        va2 = *(const uint4*)(vbase + (size_t)r2 * 1024 + slot * 16);
        va3 = *(const uint4*)(vbase + (size_t)r3 * 1024 + slot * 16);
    }

    // --- softmax over j: two register-lean float4 passes over s_att[h][*]
    {
        float mx = -1e30f;
        #pragma unroll
        for (int t = 0; t < 8; ++t) {
            const float4 w = *(const float4*)&s_att[h][t * 4];
            mx = fmaxf(mx, fmaxf(fmaxf(w.x, w.y), fmaxf(w.z, w.w)));
        }
        float s0 = 0.f, s1 = 0.f;
        #pragma unroll
        for (int t = 0; t < 8; ++t) {
            const float4 w = *(const float4*)&s_att[h][t * 4];
            s0 += __expf(w.x - mx) + __expf(w.z - mx);
            s1 += __expf(w.y - mx) + __expf(w.w - mx);
        }
        float aval = __expf(logit - mx) / (s0 + s1);
        if (rowj < 0) aval = 0.0f;
        s_att2[h][j] = aval;
    }
    __syncthreads();

    // --- att weights for out_scalar (float4 broadcast reads)
    const float4 w0 = *(const float4*)&s_att2[hh][jg * 8];
    const float4 w1 = *(const float4*)&s_att2[hh][jg * 8 + 4];

    // --- out_scalar part A (consume va)
    float acc0 = 0.f, acc1 = 0.f, acc2 = 0.f, acc3 = 0.f;
    float acc4 = 0.f, acc5 = 0.f, acc6 = 0.f, acc7 = 0.f;
    {
        const float a0 = w0.x, a1 = w0.y, a2 = w0.z, a3 = w0.w;
        acc0 = fmaf(a0, bl16(va0.x), acc0); acc1 = fmaf(a0, bh16(va0.x), acc1);
        acc2 = fmaf(a0, bl16(va0.y), acc2); acc3 = fmaf(a0, bh16(va0.y), acc3);
        acc4 = fmaf(a0, bl16(va0.z), acc4); acc5 = fmaf(a0, bh16(va0.z), acc5);
        acc6 = fmaf(a0, bl16(va0.w), acc6); acc7 = fmaf(a0, bh16(va0.w), acc7);
        acc0 = fmaf(a1, bl16(va1.x), acc0); acc1 = fmaf(a1, bh16(va1.x), acc1);
        acc2 = fmaf(a1, bl16(va1.y), acc2); acc3 = fmaf(a1, bh16(va1.y), acc3);
        acc4 = fmaf(a1, bl16(va1.z), acc4); acc5 = fmaf(a1, bh16(va1.z), acc5);
        acc6 = fmaf(a1, bl16(va1.w), acc6); acc7 = fmaf(a1, bh16(va1.w), acc7);
        acc0 = fmaf(a2, bl16(va2.x), acc0); acc1 = fmaf(a2, bh16(va2.x), acc1);
        acc2 = fmaf(a2, bl16(va2.y), acc2); acc3 = fmaf(a2, bh16(va2.y), acc3);
        acc4 = fmaf(a2, bl16(va2.z), acc4); acc5 = fmaf(a2, bh16(va2.z), acc5);
        acc6 = fmaf(a2, bl16(va2.w), acc6); acc7 = fmaf(a2, bh16(va2.w), acc7);
        acc0 = fmaf(a3, bl16(va3.x), acc0); acc1 = fmaf(a3, bh16(va3.x), acc1);
        acc2 = fmaf(a3, bl16(va3.y), acc2); acc3 = fmaf(a3, bh16(va3.y), acc3);
        acc4 = fmaf(a3, bl16(va3.z), acc4); acc5 = fmaf(a3, bh16(va3.z), acc5);
        acc6 = fmaf(a3, bl16(va3.w), acc6); acc7 = fmaf(a3, bh16(va3.w), acc7);
    }
    asm volatile("" ::: "memory");
    // --- issue v second half; latency hidden under out_pair
    uint4 vb0, vb1, vb2, vb3;
    {
        const int r4 = s_nb[jg * 8 + 4] < 0 ? 0 : s_nb[jg * 8 + 4];
        const int r5 = s_nb[jg * 8 + 5] < 0 ? 0 : s_nb[jg * 8 + 5];
        const int r6 = s_nb[jg * 8 + 6] < 0 ? 0 : s_nb[jg * 8 + 6];
        const int r7 = s_nb[jg * 8 + 7] < 0 ? 0 : s_nb[jg * 8 + 7];
        vb0 = *(const uint4*)(vbase + (size_t)r4 * 1024 + slot * 16);
        vb1 = *(const uint4*)(vbase + (size_t)r5 * 1024 + slot * 16);
        vb2 = *(const uint4*)(vbase + (size_t)r6 * 1024 + slot * 16);
        vb3 = *(const uint4*)(vbase + (size_t)r7 * 1024 + slot * 16);
    }
    asm volatile("" ::: "memory");

    // --- out_pair[h,c] -> cat[i, h*128+c]; att float4 reads, pair b64 reads
    {
        const int h2 = tid >> 5;
        const int c0 = (tid & 31) * 4;
        float4 aA = make_float4(0.f, 0.f, 0.f, 0.f);
        float4 aB = make_float4(0.f, 0.f, 0.f, 0.f);
        #pragma unroll
        for (int t = 0; t < 8; ++t) {
            const float4 aw = *(const float4*)&s_att2[h2][t * 4];
            const uint2 p0 = *(const uint2*)&s_pairb[t * 4 + 0][c0];
            const uint2 p1 = *(const uint2*)&s_pairb[t * 4 + 1][c0];
            const uint2 p2 = *(const uint2*)&s_pairb[t * 4 + 2][c0];
            const uint2 p3 = *(const uint2*)&s_pairb[t * 4 + 3][c0];
            aA.x = fmaf(aw.x, bl16(p0.x), aA.x); aA.y = fmaf(aw.x, bh16(p0.x), aA.y);
            aA.z = fmaf(aw.x, bl16(p0.y), aA.z); aA.w = fmaf(aw.x, bh16(p0.y), aA.w);
            aB.x = fmaf(aw.y, bl16(p1.x), aB.x); aB.y = fmaf(aw.y, bh16(p1.x), aB.y);
            aB.z = fmaf(aw.y, bl16(p1.y), aB.z); aB.w = fmaf(aw.y, bh16(p1.y), aB.w);
            aA.x = fmaf(aw.z, bl16(p2.x), aA.x); aA.y = fmaf(aw.z, bh16(p2.x), aA.y);
            aA.z = fmaf(aw.z, bl16(p2.y), aA.z); aA.w = fmaf(aw.z, bh16(p2.y), aA.w);
            aB.x = fmaf(aw.w, bl16(p3.x), aB.x); aB.y = fmaf(aw.w, bh16(p3.x), aB.y);
            aB.z = fmaf(aw.w, bl16(p3.y), aB.z); aB.w = fmaf(aw.w, bh16(p3.y), aB.w);
        }
        ushort4 o;
        o.x = bf2u(aA.x + aB.x); o.y = bf2u(aA.y + aB.y);
        o.z = bf2u(aA.z + aB.z); o.w = bf2u(aA.w + aB.w);
        *(ushort4*)&cat[(size_t)i * DCAT + h2 * CPD + c0] = o;
    }

    // --- out_scalar part B (consume vb) + reduce + store
    {
        const float a4 = w1.x, a5 = w1.y, a6 = w1.z, a7 = w1.w;
        acc0 = fmaf(a4, bl16(vb0.x), acc0); acc1 = fmaf(a4, bh16(vb0.x), acc1);
        acc2 = fmaf(a4, bl16(vb0.y), acc2); acc3 = fmaf(a4, bh16(vb0.y), acc3);
        acc4 = fmaf(a4, bl16(vb0.z), acc4); acc5 = fmaf(a4, bh16(vb0.z), acc5);
        acc6 = fmaf(a4, bl16(vb0.w), acc6); acc7 = fmaf(a4, bh16(vb0.w), acc7);
        acc0 = fmaf(a5, bl16(vb1.x), acc0); acc1 = fmaf(a5, bh16(vb1.x), acc1);
        acc2 = fmaf(a5, bl16(vb1.y), acc2); acc3 = fmaf(a5, bh16(vb1.y), acc3);
        acc4 = fmaf(a5, bl16(vb1.z), acc4); acc5 = fmaf(a5, bh16(vb1.z), acc5);
        acc6 = fmaf(a5, bl16(vb1.w), acc6); acc7 = fmaf(a5, bh16(vb1.w), acc7);
        acc0 = fmaf(a6, bl16(vb2.x), acc0); acc1 = fmaf(a6, bh16(vb2.x), acc1);
        acc2 = fmaf(a6, bl16(vb2.y), acc2); acc3 = fmaf(a6, bh16(vb2.y), acc3);
        acc4 = fmaf(a6, bl16(vb2.z), acc4); acc5 = fmaf(a6, bh16(vb2.z), acc5);
        acc6 = fmaf(a6, bl16(vb2.w), acc6); acc7 = fmaf(a6, bh16(vb2.w), acc7);
        acc0 = fmaf(a7, bl16(vb3.x), acc0); acc1 = fmaf(a7, bh16(vb3.x), acc1);
        acc2 = fmaf(a7, bl16(vb3.y), acc2); acc3 = fmaf(a7, bh16(vb3.y), acc3);
        acc4 = fmaf(a7, bl16(vb3.z), acc4); acc5 = fmaf(a7, bh16(vb3.z), acc5);
        acc6 = fmaf(a7, bl16(vb3.w), acc6); acc7 = fmaf(a7, bh16(vb3.w), acc7);
    }
    acc0 += __shfl_xor(acc0, 16); acc0 += __shfl_xor(acc0, 32);
    acc1 += __shfl_xor(acc1, 16); acc1 += __shfl_xor(acc1, 32);
    acc2 += __shfl_xor(acc2, 16); acc2 += __shfl_xor(acc2, 32);
    acc3 += __shfl_xor(acc3, 16); acc3 += __shfl_xor(acc3, 32);
    acc4 += __shfl_xor(acc4, 16); acc4 += __shfl_xor(acc4, 32);
    acc5 += __shfl_xor(acc5, 16); acc5 += __shfl_xor(acc5, 32);
    acc6 += __shfl_xor(acc6, 16); acc6 += __shfl_xor(acc6, 32);
    acc7 += __shfl_xor(acc7, 16); acc7 += __shfl_xor(acc7, 32);
    if (jg == 0) {
        short8 o;
        o[0] = (short)bf2u(acc0); o[1] = (short)bf2u(acc1);
        o[2] = (short)bf2u(acc2); o[3] = (short)bf2u(acc3);
        o[4] = (short)bf2u(acc4); o[5] = (short)bf2u(acc5);
        o[6] = (short)bf2u(acc6); o[7] = (short)bf2u(acc7);
        char* dst = (char*)cat + ((size_t)i * DCAT + NH * CPD) * 2 + slot * 16;
        *(short8*)dst = o;
    }
}

extern "C" void kernel_launch(void* const* d_in, const int* in_sizes, int n_in,
                              void* d_out, int out_size, void* d_ws, size_t ws_size,
                              hipStream_t stream)
{
    const float* local  = (const float*)d_in[0];
    const float* pair   = (const float*)d_in[1];
    const int*   nbr    = (const int*)d_in[2];
    const float* w_qkv  = (const float*)d_in[4];
    const float* g_q    = (const float*)d_in[5];
    const float* b_q    = (const float*)d_in[6];
    const float* g_k    = (const float*)d_in[7];
    const float* b_k    = (const float*)d_in[8];
    const float* w_bias = (const float*)d_in[9];
    const float* w_out  = (const float*)d_in[10];
    const float* b_out  = (const float*)d_in[11];
    float* out = (float*)d_out;

    char* base = (char*)d_ws;
    float*          qkv   = (float*)base;                          // [N,1536] fp32
    __hip_bfloat16* cat_b = (__hip_bfloat16*)base;                 // aliases qkv after LN
    ushort*         lc    = (ushort*)(base + 100663296u);
    __hip_bfloat16* wqkvT = (__hip_bfloat16*)(base + 117440512u);
    __hip_bfloat16* woutT = (__hip_bfloat16*)(base + 119013376u);
    __hip_bfloat16* qc    = (__hip_bfloat16*)(base + 120586240u);
    __hip_bfloat16* kc    = (__hip_bfloat16*)(base + 137363456u);
    __hip_bfloat16* vc    = (__hip_bfloat16*)(base + 154140672u);

    cvt_bf16_kernel<<<(NTOK * CDIM / 4 + 255) / 256, 256, 0, stream>>>(
        (const float4*)local, (ushort4*)lc, NTOK * CDIM / 4);
    transpose_cvt<<<dim3(QKV_W / 32, CDIM / 32), 256, 0, stream>>>(w_qkv, wqkvT, CDIM, QKV_W);
    transpose_cvt<<<dim3(CDIM / 32, DCAT / 32), 256, 0, stream>>>(w_out, woutT, DCAT, CDIM);

    hipLaunchKernelGGL((gemm_bf16<false>), dim3(QKV_W / 128, NTOK / 128), dim3(256), 0, stream,
                       lc, (const ushort*)wqkvT, nullptr, qkv, NTOK, QKV_W, CDIM);

    ln_kernel<<<NTOK * NH / 4, 256, 0, stream>>>(qkv, g_q, b_q, g_k, b_k, qc, kc, vc);

    attn_kernel<<<NTOK, 256, 0, stream>>>(qc, kc, vc, pair, nbr, w_bias, cat_b);

    hipLaunchKernelGGL((gemm_bf16<true>), dim3(CDIM / 128, NTOK / 128), dim3(256), 0, stream,
                       (const ushort*)cat_b, (const ushort*)woutT, b_out, out, NTOK, CDIM, DCAT);
}

// Round 8
// 358.204 us; speedup vs baseline: 6.7046x; 2.5917x over previous
//
#include <hip/hip_runtime.h>
#include <hip/hip_bf16.h>
#include <cstdint>

#define NTOK 16384
#define CDIM 512
#define KNB 32
#define CPD 128
#define NH 8
#define SD 64
#define QKV_W 1536   // H*3*S
#define DCAT 1536    // H*CP + H*S

typedef __attribute__((ext_vector_type(8))) short short8;
typedef __attribute__((ext_vector_type(4))) float f32x4;

__device__ inline float bl16(unsigned w) { return __uint_as_float(w << 16); }
__device__ inline float bh16(unsigned w) { return __uint_as_float(w & 0xffff0000u); }

__device__ inline ushort bf2u(float x) {
    __hip_bfloat16 b = __float2bfloat16(x);
    return *(const ushort*)&b;
}

__device__ inline void gload_lds16(const void* g, void* l) {
    __builtin_amdgcn_global_load_lds((const __attribute__((address_space(1))) void*)g,
                                     (__attribute__((address_space(3))) void*)l, 16, 0, 0);
}

// ---------------- elementwise fp32 -> bf16 convert (vectorized) ----------------
__global__ __launch_bounds__(256) void cvt_bf16_kernel(const float4* __restrict__ in,
                                                       ushort4* __restrict__ out, int n4)
{
    const int idx = blockIdx.x * 256 + threadIdx.x;
    if (idx < n4) {
        const float4 v = in[idx];
        ushort4 o;
        o.x = bf2u(v.x); o.y = bf2u(v.y); o.z = bf2u(v.z); o.w = bf2u(v.w);
        out[idx] = o;
    }
}

// ---------------- transpose + convert: in [R][Cc] fp32 -> out [Cc][R] bf16 ----------------
__global__ __launch_bounds__(256) void transpose_cvt(const float* __restrict__ in,
                                                     __hip_bfloat16* __restrict__ out,
                                                     int R, int Cc)
{
    __shared__ float t[32][33];
    const int c0 = blockIdx.x * 32, r0 = blockIdx.y * 32;
    const int tx = threadIdx.x & 31, ty = threadIdx.x >> 5;
    #pragma unroll
    for (int rr = ty; rr < 32; rr += 8)
        t[rr][tx] = in[(size_t)(r0 + rr) * Cc + c0 + tx];
    __syncthreads();
    #pragma unroll
    for (int rr = ty; rr < 32; rr += 8)
        out[(size_t)(c0 + rr) * R + r0 + tx] = __float2bfloat16(t[tx][rr]);
}

// ---------------- bf16 MFMA GEMM: C[M,N] = A[M,K](bf16) @ Bt[N,K](bf16)^T (+bias) -------
template<bool ADD_BIAS>
__global__ __launch_bounds__(256) void gemm_bf16(const ushort* __restrict__ A,
                                                 const ushort* __restrict__ Bt,
                                                 const float* __restrict__ bias,
                                                 float* __restrict__ C,
                                                 int M, int N, int K)
{
    __shared__ __align__(16) ushort Asl[128 * 32];
    __shared__ __align__(16) ushort Bsl[128 * 32];

    const int tid = threadIdx.x;
    const int wave = tid >> 6;
    const int lane = tid & 63;
    const int m0 = blockIdx.y * 128;
    const int n0 = blockIdx.x * 128;
    const int wr = wave >> 1, wc = wave & 1;

    f32x4 acc[4][4] = {};

    const int st_row_in_chunk = lane >> 2;
    const int st_bcol = (lane & 3) * 16;

    const int lr = lane & 15;
    const int kg = lane >> 4;

    for (int kt = 0; kt < K; kt += 32) {
        #pragma unroll
        for (int p = 0; p < 2; ++p) {
            const int chunk = wave * 2 + p;
            const int row = chunk * 16 + st_row_in_chunk;
            const char* asrc = (const char*)(A + (size_t)(m0 + row) * K + kt) + st_bcol;
            const char* bsrc = (const char*)(Bt + (size_t)(n0 + row) * K + kt) + st_bcol;
            gload_lds16(asrc, (char*)Asl + chunk * 1024);
            gload_lds16(bsrc, (char*)Bsl + chunk * 1024);
        }
        __syncthreads();

        short8 a[4], b[4];
        #pragma unroll
        for (int m = 0; m < 4; ++m)
            a[m] = *(const short8*)&Asl[(wr * 64 + m * 16 + lr) * 32 + kg * 8];
        #pragma unroll
        for (int n = 0; n < 4; ++n)
            b[n] = *(const short8*)&Bsl[(wc * 64 + n * 16 + lr) * 32 + kg * 8];
        #pragma unroll
        for (int m = 0; m < 4; ++m)
            #pragma unroll
            for (int n = 0; n < 4; ++n)
                acc[m][n] = __builtin_amdgcn_mfma_f32_16x16x32_bf16(a[m], b[n], acc[m][n], 0, 0, 0);
        __syncthreads();
    }

    #pragma unroll
    for (int m = 0; m < 4; ++m) {
        #pragma unroll
        for (int n = 0; n < 4; ++n) {
            const int col = n0 + wc * 64 + n * 16 + lr;
            const float bv = ADD_BIAS ? bias[col] : 0.0f;
            #pragma unroll
            for (int r = 0; r < 4; ++r) {
                const int row = m0 + wr * 64 + m * 16 + kg * 4 + r;
                C[(size_t)row * N + col] = acc[m][n][r] + bv;
            }
        }
    }
}

// ---------------- LayerNorm q,k + compact bf16 q/k/v: one wave per (i,h) -------------
__global__ __launch_bounds__(256) void ln_kernel(const float* __restrict__ qkv,
                                                 const float* __restrict__ g_q,
                                                 const float* __restrict__ b_q,
                                                 const float* __restrict__ g_k,
                                                 const float* __restrict__ b_k,
                                                 __hip_bfloat16* __restrict__ qc,
                                                 __hip_bfloat16* __restrict__ kc,
                                                 __hip_bfloat16* __restrict__ vc)
{
    const int gid = blockIdx.x * 4 + (threadIdx.x >> 6);   // i*8 + h
    const int lane = threadIdx.x & 63;

    const float* p = qkv + (size_t)(gid >> 3) * QKV_W + (gid & 7) * 192;
    const float q = p[lane];
    const float k = p[64 + lane];
    const float v = p[128 + lane];

    float sq = q, sk = k;
    #pragma unroll
    for (int o = 1; o < 64; o <<= 1) { sq += __shfl_xor(sq, o); sk += __shfl_xor(sk, o); }
    const float mq = sq * (1.0f / 64.0f), mk = sk * (1.0f / 64.0f);
    const float dq = q - mq, dk = k - mk;
    float vq = dq * dq, vk = dk * dk;
    #pragma unroll
    for (int o = 1; o < 64; o <<= 1) { vq += __shfl_xor(vq, o); vk += __shfl_xor(vk, o); }
    const float iq = rsqrtf(vq * (1.0f / 64.0f) + 1e-5f);
    const float ik = rsqrtf(vk * (1.0f / 64.0f) + 1e-5f);

    const size_t o64 = (size_t)gid * 64 + lane;
    qc[o64] = __float2bfloat16(dq * iq * g_q[lane] + b_q[lane]);
    kc[o64] = __float2bfloat16(dk * ik * g_k[lane] + b_k[lane]);
    vc[o64] = __float2bfloat16(v);
}

// ---------------- fused neighbour attention: one block per token i ----------------
__global__ __launch_bounds__(256) void attn_kernel(const __hip_bfloat16* __restrict__ qc,
                                                   const __hip_bfloat16* __restrict__ kc,
                                                   const __hip_bfloat16* __restrict__ vc,
                                                   const float* __restrict__ pair,
                                                   const int* __restrict__ nbr,
                                                   const float* __restrict__ w_bias,
                                                   __hip_bfloat16* __restrict__ cat)
{
    __shared__ __align__(16) ushort s_pairb[KNB][CPD + 8];  // 8.5 KB, row 272 B
    __shared__ __align__(16) ushort s_wbTb[NH][CPD + 8];    // 2.2 KB
    __shared__ __align__(16) ushort s_qb[NH][SD + 8];       // 1.2 KB
    __shared__ __align__(16) float s_att[NH][KNB + 4];      // bias -> logits (in place)
    __shared__ __align__(16) float s_att2[NH][KNB + 4];     // softmax weights
    __shared__ int s_nb[KNB];

    const int i = blockIdx.x;
    const int tid = threadIdx.x;
    const int j = tid >> 3;
    const int h = tid & 7;
    const int wave = tid >> 6;
    const int lane = tid & 63;

    // --- k-gather first half pre-barrier (latency hides under staging)
    const int rowj = nbr[i * KNB + j];
    const int rk = rowj < 0 ? 0 : rowj;
    const uint4* kp = (const uint4*)(kc + ((size_t)rk * NH + h) * SD);
    uint4 ka0 = kp[0], ka1 = kp[1], ka2 = kp[2], ka3 = kp[3];

    // --- LDS staging
    if (tid < KNB) s_nb[tid] = nbr[i * KNB + tid];
    if (tid < 64) {   // q already bf16: straight uint4 copy
        const uint4 qw = ((const uint4*)(qc + (size_t)i * 512))[tid];
        *(uint4*)&s_qb[tid >> 3][(tid & 7) * 8] = qw;
    }
    {   // w_bias [128][8] fp32 -> s_wbTb[h][c] bf16
        const float4 w4 = ((const float4*)w_bias)[tid];
        const int c = tid >> 1;
        const int h0 = (tid & 1) * 4;
        s_wbTb[h0 + 0][c] = bf2u(w4.x);
        s_wbTb[h0 + 1][c] = bf2u(w4.y);
        s_wbTb[h0 + 2][c] = bf2u(w4.z);
        s_wbTb[h0 + 3][c] = bf2u(w4.w);
    }
    {   // pair tile fp32 -> bf16 LDS
        const float4* pr = (const float4*)(pair + (size_t)i * KNB * CPD);
        #pragma unroll
        for (int t2 = 0; t2 < 2; ++t2) {
            const int ch = t2 * 256 + tid;
            const int row = ch >> 4;
            const int c8 = (ch & 15) * 8;
            const float4 a = pr[row * 32 + (c8 >> 2)];
            const float4 b = pr[row * 32 + (c8 >> 2) + 1];
            short8 o;
            o[0] = (short)bf2u(a.x); o[1] = (short)bf2u(a.y);
            o[2] = (short)bf2u(a.z); o[3] = (short)bf2u(a.w);
            o[4] = (short)bf2u(b.x); o[5] = (short)bf2u(b.y);
            o[6] = (short)bf2u(b.z); o[7] = (short)bf2u(b.w);
            *(short8*)&s_pairb[row][c8] = o;
        }
    }
    __syncthreads();

    // --- issue k second half immediately (r5-proven placement; hides under dot part 1)
    uint4 kb0 = kp[4], kb1 = kp[5], kb2 = kp[6], kb3 = kp[7];

    // --- dot part 1: consume ka (frees 16 regs before the MFMA window)
    const uint4* qrow = (const uint4*)&s_qb[h][0];
    float d0 = 0.f, d1 = 0.f, d2 = 0.f, d3 = 0.f;
    #pragma unroll
    for (int u = 0; u < 4; ++u) {
        uint4 K;
        switch (u) { case 0: K = ka0; break; case 1: K = ka1; break;
                     case 2: K = ka2; break; default: K = ka3; break; }
        const uint4 Q = qrow[u];
        d0 = fmaf(bl16(K.x), bl16(Q.x), fmaf(bh16(K.x), bh16(Q.x), d0));
        d1 = fmaf(bl16(K.y), bl16(Q.y), fmaf(bh16(K.y), bh16(Q.y), d1));
        d2 = fmaf(bl16(K.z), bl16(Q.z), fmaf(bh16(K.z), bh16(Q.z), d2));
        d3 = fmaf(bl16(K.w), bl16(Q.w), fmaf(bh16(K.w), bh16(Q.w), d3));
    }

    // --- waves 0,1: bias = P @ Wb via MFMA (tile rows j 0-15 / 16-31); ka regs now dead
    if (wave < 2) {
        const int lr = lane & 15;
        const int kg = lane >> 4;
        f32x4 cacc = {};
        const ushort* arow = &s_pairb[wave * 16 + lr][kg * 8];
        const ushort* brow = &s_wbTb[lr & 7][kg * 8];   // cols n>=8 read aliased rows, discarded
        #pragma unroll
        for (int ks = 0; ks < 4; ++ks) {
            const short8 af = *(const short8*)(arow + ks * 32);
            const short8 bf = *(const short8*)(brow + ks * 32);
            cacc = __builtin_amdgcn_mfma_f32_16x16x32_bf16(af, bf, cacc, 0, 0, 0);
        }
        if (lr < 8) {   // C: col h = lr, row j = wave*16 + kg*4 + r
            const int jj = wave * 16 + kg * 4;
            s_att[lr][jj + 0] = cacc[0];
            s_att[lr][jj + 1] = cacc[1];
            s_att[lr][jj + 2] = cacc[2];
            s_att[lr][jj + 3] = cacc[3];
        }
    }

    // --- dot part 2: consume kb
    #pragma unroll
    for (int u = 0; u < 4; ++u) {
        uint4 K;
        switch (u) { case 0: K = kb0; break; case 1: K = kb1; break;
                     case 2: K = kb2; break; default: K = kb3; break; }
        const uint4 Q = qrow[u + 4];
        d0 = fmaf(bl16(K.x), bl16(Q.x), fmaf(bh16(K.x), bh16(Q.x), d0));
        d1 = fmaf(bl16(K.y), bl16(Q.y), fmaf(bh16(K.y), bh16(Q.y), d1));
        d2 = fmaf(bl16(K.z), bl16(Q.z), fmaf(bh16(K.z), bh16(Q.z), d2));
        d3 = fmaf(bl16(K.w), bl16(Q.w), fmaf(bh16(K.w), bh16(Q.w), d3));
    }
    __syncthreads();   // MFMA bias in s_att visible to all

    // --- logit = w_L*(dot/8 + bias); in-place update of s_att[h][j]
    float logit = -1e9f;
    if (rowj >= 0) {
        const float dot = (d0 + d1) + (d2 + d3);
        logit = 0.70710678118f * (dot * 0.125f + s_att[h][j]);
    }
    s_att[h][j] = logit;
    __syncthreads();

    // --- out_scalar mapping + v-gather first half (latency hides under softmax)
    const int slot = wave * 16 + (lane & 15);   // h = slot>>3, 16B chunk = slot&7
    const int jg = lane >> 4;                   // owns rows jg*8 .. jg*8+7
    const int hh = slot >> 3;
    const char* vbase = (const char*)vc;
    uint4 va0, va1, va2, va3;
    {
        const int r0 = s_nb[jg * 8 + 0] < 0 ? 0 : s_nb[jg * 8 + 0];
        const int r1 = s_nb[jg * 8 + 1] < 0 ? 0 : s_nb[jg * 8 + 1];
        const int r2 = s_nb[jg * 8 + 2] < 0 ? 0 : s_nb[jg * 8 + 2];
        const int r3 = s_nb[jg * 8 + 3] < 0 ? 0 : s_nb[jg * 8 + 3];
        va0 = *(const uint4*)(vbase + (size_t)r0 * 1024 + slot * 16);
        va1 = *(const uint4*)(vbase + (size_t)r1 * 1024 + slot * 16);
        va2 = *(const uint4*)(vbase + (size_t)r2 * 1024 + slot * 16);
        va3 = *(const uint4*)(vbase + (size_t)r3 * 1024 + slot * 16);
    }

    // --- softmax over j: two register-lean float4 passes over s_att[h][*]
    {
        float mx = -1e30f;
        #pragma unroll
        for (int t = 0; t < 8; ++t) {
            const float4 w = *(const float4*)&s_att[h][t * 4];
            mx = fmaxf(mx, fmaxf(fmaxf(w.x, w.y), fmaxf(w.z, w.w)));
        }
        float s0 = 0.f, s1 = 0.f;
        #pragma unroll
        for (int t = 0; t < 8; ++t) {
            const float4 w = *(const float4*)&s_att[h][t * 4];
            s0 += __expf(w.x - mx) + __expf(w.z - mx);
            s1 += __expf(w.y - mx) + __expf(w.w - mx);
        }
        float aval = __expf(logit - mx) / (s0 + s1);
        if (rowj < 0) aval = 0.0f;
        s_att2[h][j] = aval;
    }
    __syncthreads();

    // --- att weights for out_scalar (float4 broadcast reads)
    const float4 w0 = *(const float4*)&s_att2[hh][jg * 8];
    const float4 w1 = *(const float4*)&s_att2[hh][jg * 8 + 4];

    // --- out_scalar part A (consume va)
    float acc0 = 0.f, acc1 = 0.f, acc2 = 0.f, acc3 = 0.f;
    float acc4 = 0.f, acc5 = 0.f, acc6 = 0.f, acc7 = 0.f;
    {
        const float a0 = w0.x, a1 = w0.y, a2 = w0.z, a3 = w0.w;
        acc0 = fmaf(a0, bl16(va0.x), acc0); acc1 = fmaf(a0, bh16(va0.x), acc1);
        acc2 = fmaf(a0, bl16(va0.y), acc2); acc3 = fmaf(a0, bh16(va0.y), acc3);
        acc4 = fmaf(a0, bl16(va0.z), acc4); acc5 = fmaf(a0, bh16(va0.z), acc5);
        acc6 = fmaf(a0, bl16(va0.w), acc6); acc7 = fmaf(a0, bh16(va0.w), acc7);
        acc0 = fmaf(a1, bl16(va1.x), acc0); acc1 = fmaf(a1, bh16(va1.x), acc1);
        acc2 = fmaf(a1, bl16(va1.y), acc2); acc3 = fmaf(a1, bh16(va1.y), acc3);
        acc4 = fmaf(a1, bl16(va1.z), acc4); acc5 = fmaf(a1, bh16(va1.z), acc5);
        acc6 = fmaf(a1, bl16(va1.w), acc6); acc7 = fmaf(a1, bh16(va1.w), acc7);
        acc0 = fmaf(a2, bl16(va2.x), acc0); acc1 = fmaf(a2, bh16(va2.x), acc1);
        acc2 = fmaf(a2, bl16(va2.y), acc2); acc3 = fmaf(a2, bh16(va2.y), acc3);
        acc4 = fmaf(a2, bl16(va2.z), acc4); acc5 = fmaf(a2, bh16(va2.z), acc5);
        acc6 = fmaf(a2, bl16(va2.w), acc6); acc7 = fmaf(a2, bh16(va2.w), acc7);
        acc0 = fmaf(a3, bl16(va3.x), acc0); acc1 = fmaf(a3, bh16(va3.x), acc1);
        acc2 = fmaf(a3, bl16(va3.y), acc2); acc3 = fmaf(a3, bh16(va3.y), acc3);
        acc4 = fmaf(a3, bl16(va3.z), acc4); acc5 = fmaf(a3, bh16(va3.z), acc5);
        acc6 = fmaf(a3, bl16(va3.w), acc6); acc7 = fmaf(a3, bh16(va3.w), acc7);
    }
    asm volatile("" ::: "memory");
    // --- issue v second half; latency hidden under out_pair
    uint4 vb0, vb1, vb2, vb3;
    {
        const int r4 = s_nb[jg * 8 + 4] < 0 ? 0 : s_nb[jg * 8 + 4];
        const int r5 = s_nb[jg * 8 + 5] < 0 ? 0 : s_nb[jg * 8 + 5];
        const int r6 = s_nb[jg * 8 + 6] < 0 ? 0 : s_nb[jg * 8 + 6];
        const int r7 = s_nb[jg * 8 + 7] < 0 ? 0 : s_nb[jg * 8 + 7];
        vb0 = *(const uint4*)(vbase + (size_t)r4 * 1024 + slot * 16);
        vb1 = *(const uint4*)(vbase + (size_t)r5 * 1024 + slot * 16);
        vb2 = *(const uint4*)(vbase + (size_t)r6 * 1024 + slot * 16);
        vb3 = *(const uint4*)(vbase + (size_t)r7 * 1024 + slot * 16);
    }
    asm volatile("" ::: "memory");

    // --- out_pair[h,c] -> cat[i, h*128+c]; att float4 reads, pair b64 reads
    {
        const int h2 = tid >> 5;
        const int c0 = (tid & 31) * 4;
        float4 aA = make_float4(0.f, 0.f, 0.f, 0.f);
        float4 aB = make_float4(0.f, 0.f, 0.f, 0.f);
        #pragma unroll
        for (int t = 0; t < 8; ++t) {
            const float4 aw = *(const float4*)&s_att2[h2][t * 4];
            const uint2 p0 = *(const uint2*)&s_pairb[t * 4 + 0][c0];
            const uint2 p1 = *(const uint2*)&s_pairb[t * 4 + 1][c0];
            const uint2 p2 = *(const uint2*)&s_pairb[t * 4 + 2][c0];
            const uint2 p3 = *(const uint2*)&s_pairb[t * 4 + 3][c0];
            aA.x = fmaf(aw.x, bl16(p0.x), aA.x); aA.y = fmaf(aw.x, bh16(p0.x), aA.y);
            aA.z = fmaf(aw.x, bl16(p0.y), aA.z); aA.w = fmaf(aw.x, bh16(p0.y), aA.w);
            aB.x = fmaf(aw.y, bl16(p1.x), aB.x); aB.y = fmaf(aw.y, bh16(p1.x), aB.y);
            aB.z = fmaf(aw.y, bl16(p1.y), aB.z); aB.w = fmaf(aw.y, bh16(p1.y), aB.w);
            aA.x = fmaf(aw.z, bl16(p2.x), aA.x); aA.y = fmaf(aw.z, bh16(p2.x), aA.y);
            aA.z = fmaf(aw.z, bl16(p2.y), aA.z); aA.w = fmaf(aw.z, bh16(p2.y), aA.w);
            aB.x = fmaf(aw.w, bl16(p3.x), aB.x); aB.y = fmaf(aw.w, bh16(p3.x), aB.y);
            aB.z = fmaf(aw.w, bl16(p3.y), aB.z); aB.w = fmaf(aw.w, bh16(p3.y), aB.w);
        }
        ushort4 o;
        o.x = bf2u(aA.x + aB.x); o.y = bf2u(aA.y + aB.y);
        o.z = bf2u(aA.z + aB.z); o.w = bf2u(aA.w + aB.w);
        *(ushort4*)&cat[(size_t)i * DCAT + h2 * CPD + c0] = o;
    }

    // --- out_scalar part B (consume vb) + reduce + store
    {
        const float a4 = w1.x, a5 = w1.y, a6 = w1.z, a7 = w1.w;
        acc0 = fmaf(a4, bl16(vb0.x), acc0); acc1 = fmaf(a4, bh16(vb0.x), acc1);
        acc2 = fmaf(a4, bl16(vb0.y), acc2); acc3 = fmaf(a4, bh16(vb0.y), acc3);
        acc4 = fmaf(a4, bl16(vb0.z), acc4); acc5 = fmaf(a4, bh16(vb0.z), acc5);
        acc6 = fmaf(a4, bl16(vb0.w), acc6); acc7 = fmaf(a4, bh16(vb0.w), acc7);
        acc0 = fmaf(a5, bl16(vb1.x), acc0); acc1 = fmaf(a5, bh16(vb1.x), acc1);
        acc2 = fmaf(a5, bl16(vb1.y), acc2); acc3 = fmaf(a5, bh16(vb1.y), acc3);
        acc4 = fmaf(a5, bl16(vb1.z), acc4); acc5 = fmaf(a5, bh16(vb1.z), acc5);
        acc6 = fmaf(a5, bl16(vb1.w), acc6); acc7 = fmaf(a5, bh16(vb1.w), acc7);
        acc0 = fmaf(a6, bl16(vb2.x), acc0); acc1 = fmaf(a6, bh16(vb2.x), acc1);
        acc2 = fmaf(a6, bl16(vb2.y), acc2); acc3 = fmaf(a6, bh16(vb2.y), acc3);
        acc4 = fmaf(a6, bl16(vb2.z), acc4); acc5 = fmaf(a6, bh16(vb2.z), acc5);
        acc6 = fmaf(a6, bl16(vb2.w), acc6); acc7 = fmaf(a6, bh16(vb2.w), acc7);
        acc0 = fmaf(a7, bl16(vb3.x), acc0); acc1 = fmaf(a7, bh16(vb3.x), acc1);
        acc2 = fmaf(a7, bl16(vb3.y), acc2); acc3 = fmaf(a7, bh16(vb3.y), acc3);
        acc4 = fmaf(a7, bl16(vb3.z), acc4); acc5 = fmaf(a7, bh16(vb3.z), acc5);
        acc6 = fmaf(a7, bl16(vb3.w), acc6); acc7 = fmaf(a7, bh16(vb3.w), acc7);
    }
    acc0 += __shfl_xor(acc0, 16); acc0 += __shfl_xor(acc0, 32);
    acc1 += __shfl_xor(acc1, 16); acc1 += __shfl_xor(acc1, 32);
    acc2 += __shfl_xor(acc2, 16); acc2 += __shfl_xor(acc2, 32);
    acc3 += __shfl_xor(acc3, 16); acc3 += __shfl_xor(acc3, 32);
    acc4 += __shfl_xor(acc4, 16); acc4 += __shfl_xor(acc4, 32);
    acc5 += __shfl_xor(acc5, 16); acc5 += __shfl_xor(acc5, 32);
    acc6 += __shfl_xor(acc6, 16); acc6 += __shfl_xor(acc6, 32);
    acc7 += __shfl_xor(acc7, 16); acc7 += __shfl_xor(acc7, 32);
    if (jg == 0) {
        short8 o;
        o[0] = (short)bf2u(acc0); o[1] = (short)bf2u(acc1);
        o[2] = (short)bf2u(acc2); o[3] = (short)bf2u(acc3);
        o[4] = (short)bf2u(acc4); o[5] = (short)bf2u(acc5);
        o[6] = (short)bf2u(acc6); o[7] = (short)bf2u(acc7);
        char* dst = (char*)cat + ((size_t)i * DCAT + NH * CPD) * 2 + slot * 16;
        *(short8*)dst = o;
    }
}

extern "C" void kernel_launch(void* const* d_in, const int* in_sizes, int n_in,
                              void* d_out, int out_size, void* d_ws, size_t ws_size,
                              hipStream_t stream)
{
    const float* local  = (const float*)d_in[0];
    const float* pair   = (const float*)d_in[1];
    const int*   nbr    = (const int*)d_in[2];
    const float* w_qkv  = (const float*)d_in[4];
    const float* g_q    = (const float*)d_in[5];
    const float* b_q    = (const float*)d_in[6];
    const float* g_k    = (const float*)d_in[7];
    const float* b_k    = (const float*)d_in[8];
    const float* w_bias = (const float*)d_in[9];
    const float* w_out  = (const float*)d_in[10];
    const float* b_out  = (const float*)d_in[11];
    float* out = (float*)d_out;

    char* base = (char*)d_ws;
    float*          qkv   = (float*)base;                          // [N,1536] fp32
    __hip_bfloat16* cat_b = (__hip_bfloat16*)base;                 // aliases qkv after LN
    ushort*         lc    = (ushort*)(base + 100663296u);
    __hip_bfloat16* wqkvT = (__hip_bfloat16*)(base + 117440512u);
    __hip_bfloat16* woutT = (__hip_bfloat16*)(base + 119013376u);
    __hip_bfloat16* qc    = (__hip_bfloat16*)(base + 120586240u);
    __hip_bfloat16* kc    = (__hip_bfloat16*)(base + 137363456u);
    __hip_bfloat16* vc    = (__hip_bfloat16*)(base + 154140672u);

    cvt_bf16_kernel<<<(NTOK * CDIM / 4 + 255) / 256, 256, 0, stream>>>(
        (const float4*)local, (ushort4*)lc, NTOK * CDIM / 4);
    transpose_cvt<<<dim3(QKV_W / 32, CDIM / 32), 256, 0, stream>>>(w_qkv, wqkvT, CDIM, QKV_W);
    transpose_cvt<<<dim3(CDIM / 32, DCAT / 32), 256, 0, stream>>>(w_out, woutT, DCAT, CDIM);

    hipLaunchKernelGGL((gemm_bf16<false>), dim3(QKV_W / 128, NTOK / 128), dim3(256), 0, stream,
                       lc, (const ushort*)wqkvT, nullptr, qkv, NTOK, QKV_W, CDIM);

    ln_kernel<<<NTOK * NH / 4, 256, 0, stream>>>(qkv, g_q, b_q, g_k, b_k, qc, kc, vc);

    attn_kernel<<<NTOK, 256, 0, stream>>>(qc, kc, vc, pair, nbr, w_bias, cat_b);

    hipLaunchKernelGGL((gemm_bf16<true>), dim3(CDIM / 128, NTOK / 128), dim3(256), 0, stream,
                       (const ushort*)cat_b, (const ushort*)woutT, b_out, out, NTOK, CDIM, DCAT);
}

// Round 10
// 352.398 us; speedup vs baseline: 6.8150x; 1.0165x over previous
//
#include <hip/hip_runtime.h>
#include <hip/hip_bf16.h>
#include <cstdint>

#define NTOK 16384
#define CDIM 512
#define KNB 32
#define CPD 128
#define NH 8
#define SD 64
#define QKV_W 1536   // H*3*S
#define DCAT 1536    // H*CP + H*S

typedef __attribute__((ext_vector_type(8))) short short8;
typedef __attribute__((ext_vector_type(4))) float f32x4;

__device__ inline float bl16(unsigned w) { return __uint_as_float(w << 16); }
__device__ inline float bh16(unsigned w) { return __uint_as_float(w & 0xffff0000u); }
__device__ inline float u16f(ushort u) { return __uint_as_float(((unsigned)u) << 16); }

__device__ inline ushort bf2u(float x) {
    __hip_bfloat16 b = __float2bfloat16(x);
    return *(const ushort*)&b;
}

__device__ inline void gload_lds16(const void* g, void* l) {
    __builtin_amdgcn_global_load_lds((const __attribute__((address_space(1))) void*)g,
                                     (__attribute__((address_space(3))) void*)l, 16, 0, 0);
}

// ---------------- elementwise fp32 -> bf16 convert (vectorized) ----------------
__global__ __launch_bounds__(256) void cvt_bf16_kernel(const float4* __restrict__ in,
                                                       ushort4* __restrict__ out, int n4)
{
    const int idx = blockIdx.x * 256 + threadIdx.x;
    if (idx < n4) {
        const float4 v = in[idx];
        ushort4 o;
        o.x = bf2u(v.x); o.y = bf2u(v.y); o.z = bf2u(v.z); o.w = bf2u(v.w);
        out[idx] = o;
    }
}

// ---------------- transpose + convert: in [R][Cc] fp32 -> out [Cc][R] bf16 ----------------
__global__ __launch_bounds__(256) void transpose_cvt(const float* __restrict__ in,
                                                     __hip_bfloat16* __restrict__ out,
                                                     int R, int Cc)
{
    __shared__ float t[32][33];
    const int c0 = blockIdx.x * 32, r0 = blockIdx.y * 32;
    const int tx = threadIdx.x & 31, ty = threadIdx.x >> 5;
    #pragma unroll
    for (int rr = ty; rr < 32; rr += 8)
        t[rr][tx] = in[(size_t)(r0 + rr) * Cc + c0 + tx];
    __syncthreads();
    #pragma unroll
    for (int rr = ty; rr < 32; rr += 8)
        out[(size_t)(c0 + rr) * R + r0 + tx] = __float2bfloat16(t[tx][rr]);
}

// ---------------- bf16 MFMA GEMM: C[M,N] = A[M,K](bf16) @ Bt[N,K](bf16)^T (+bias) -------
template<bool ADD_BIAS, bool OUT_BF16>
__global__ __launch_bounds__(256) void gemm_bf16(const ushort* __restrict__ A,
                                                 const ushort* __restrict__ Bt,
                                                 const float* __restrict__ bias,
                                                 void* __restrict__ Cv,
                                                 int M, int N, int K)
{
    __shared__ __align__(16) ushort Asl[128 * 32];
    __shared__ __align__(16) ushort Bsl[128 * 32];

    const int tid = threadIdx.x;
    const int wave = tid >> 6;
    const int lane = tid & 63;
    const int m0 = blockIdx.y * 128;
    const int n0 = blockIdx.x * 128;
    const int wr = wave >> 1, wc = wave & 1;

    f32x4 acc[4][4] = {};

    const int st_row_in_chunk = lane >> 2;
    const int st_bcol = (lane & 3) * 16;

    const int lr = lane & 15;
    const int kg = lane >> 4;

    for (int kt = 0; kt < K; kt += 32) {
        #pragma unroll
        for (int p = 0; p < 2; ++p) {
            const int chunk = wave * 2 + p;
            const int row = chunk * 16 + st_row_in_chunk;
            const char* asrc = (const char*)(A + (size_t)(m0 + row) * K + kt) + st_bcol;
            const char* bsrc = (const char*)(Bt + (size_t)(n0 + row) * K + kt) + st_bcol;
            gload_lds16(asrc, (char*)Asl + chunk * 1024);
            gload_lds16(bsrc, (char*)Bsl + chunk * 1024);
        }
        __syncthreads();

        short8 a[4], b[4];
        #pragma unroll
        for (int m = 0; m < 4; ++m)
            a[m] = *(const short8*)&Asl[(wr * 64 + m * 16 + lr) * 32 + kg * 8];
        #pragma unroll
        for (int n = 0; n < 4; ++n)
            b[n] = *(const short8*)&Bsl[(wc * 64 + n * 16 + lr) * 32 + kg * 8];
        #pragma unroll
        for (int m = 0; m < 4; ++m)
            #pragma unroll
            for (int n = 0; n < 4; ++n)
                acc[m][n] = __builtin_amdgcn_mfma_f32_16x16x32_bf16(a[m], b[n], acc[m][n], 0, 0, 0);
        __syncthreads();
    }

    #pragma unroll
    for (int m = 0; m < 4; ++m) {
        #pragma unroll
        for (int n = 0; n < 4; ++n) {
            const int col = n0 + wc * 64 + n * 16 + lr;
            const float bv = ADD_BIAS ? bias[col] : 0.0f;
            #pragma unroll
            for (int r = 0; r < 4; ++r) {
                const int row = m0 + wr * 64 + m * 16 + kg * 4 + r;
                if (OUT_BF16)
                    ((ushort*)Cv)[(size_t)row * N + col] = bf2u(acc[m][n][r] + bv);
                else
                    ((float*)Cv)[(size_t)row * N + col] = acc[m][n][r] + bv;
            }
        }
    }
}

// ---------------- LayerNorm q,k + compact bf16 q/k/v (bf16 qkv input) -------------
__global__ __launch_bounds__(256) void ln_kernel(const ushort* __restrict__ qkvb,
                                                 const float* __restrict__ g_q,
                                                 const float* __restrict__ b_q,
                                                 const float* __restrict__ g_k,
                                                 const float* __restrict__ b_k,
                                                 __hip_bfloat16* __restrict__ qc,
                                                 __hip_bfloat16* __restrict__ kc,
                                                 __hip_bfloat16* __restrict__ vc)
{
    const int gid = blockIdx.x * 4 + (threadIdx.x >> 6);   // i*8 + h
    const int lane = threadIdx.x & 63;

    const ushort* p = qkvb + (size_t)(gid >> 3) * QKV_W + (gid & 7) * 192;
    const float q = u16f(p[lane]);
    const float k = u16f(p[64 + lane]);
    const ushort v = p[128 + lane];

    float sq = q, sk = k;
    #pragma unroll
    for (int o = 1; o < 64; o <<= 1) { sq += __shfl_xor(sq, o); sk += __shfl_xor(sk, o); }
    const float mq = sq * (1.0f / 64.0f), mk = sk * (1.0f / 64.0f);
    const float dq = q - mq, dk = k - mk;
    float vq = dq * dq, vk = dk * dk;
    #pragma unroll
    for (int o = 1; o < 64; o <<= 1) { vq += __shfl_xor(vq, o); vk += __shfl_xor(vk, o); }
    const float iq = rsqrtf(vq * (1.0f / 64.0f) + 1e-5f);
    const float ik = rsqrtf(vk * (1.0f / 64.0f) + 1e-5f);

    const size_t o64 = (size_t)gid * 64 + lane;
    qc[o64] = __float2bfloat16(dq * iq * g_q[lane] + b_q[lane]);
    kc[o64] = __float2bfloat16(dk * ik * g_k[lane] + b_k[lane]);
    *(ushort*)&vc[o64] = v;
}

// ---------------- fused neighbour attention: one block per token i ----------------
__global__ __launch_bounds__(256) void attn_kernel(const __hip_bfloat16* __restrict__ qc,
                                                   const __hip_bfloat16* __restrict__ kc,
                                                   const __hip_bfloat16* __restrict__ vc,
                                                   const float* __restrict__ pair,
                                                   const int* __restrict__ nbr,
                                                   const float* __restrict__ w_bias,
                                                   __hip_bfloat16* __restrict__ cat)
{
    __shared__ __align__(16) ushort s_pairb[KNB][CPD + 8];  // 8.5 KB, row 272 B
    __shared__ __align__(16) ushort s_wbTb[NH][CPD + 8];    // 2.2 KB
    __shared__ __align__(16) ushort s_qb[NH][SD + 8];       // 1.2 KB
    __shared__ __align__(16) float s_att[NH][KNB + 4];      // bias -> logits (in place)
    __shared__ __align__(16) float s_att2[NH][KNB + 4];     // softmax weights
    __shared__ int s_nb[KNB];

    const int i = blockIdx.x;
    const int tid = threadIdx.x;
    const int j = tid >> 3;
    const int h = tid & 7;
    const int wave = tid >> 6;
    const int lane = tid & 63;

    // --- k-gather 2-deep pipeline, phase 0 issued pre-barrier (16 regs peak)
    const int rowj = nbr[i * KNB + j];
    const int rk = rowj < 0 ? 0 : rowj;
    const uint4* kp = (const uint4*)(kc + ((size_t)rk * NH + h) * SD);
    uint4 kA0 = kp[0], kA1 = kp[1];

    // --- LDS staging
    if (tid < KNB) s_nb[tid] = nbr[i * KNB + tid];
    if (tid < 64) {   // q already bf16: straight uint4 copy
        const uint4 qw = ((const uint4*)(qc + (size_t)i * 512))[tid];
        *(uint4*)&s_qb[tid >> 3][(tid & 7) * 8] = qw;
    }
    {   // w_bias [128][8] fp32 -> s_wbTb[h][c] bf16
        const float4 w4 = ((const float4*)w_bias)[tid];
        const int c = tid >> 1;
        const int h0 = (tid & 1) * 4;
        s_wbTb[h0 + 0][c] = bf2u(w4.x);
        s_wbTb[h0 + 1][c] = bf2u(w4.y);
        s_wbTb[h0 + 2][c] = bf2u(w4.z);
        s_wbTb[h0 + 3][c] = bf2u(w4.w);
    }
    {   // pair tile fp32 -> bf16 LDS
        const float4* pr = (const float4*)(pair + (size_t)i * KNB * CPD);
        #pragma unroll
        for (int t2 = 0; t2 < 2; ++t2) {
            const int ch = t2 * 256 + tid;
            const int row = ch >> 4;
            const int c8 = (ch & 15) * 8;
            const float4 a = pr[row * 32 + (c8 >> 2)];
            const float4 b = pr[row * 32 + (c8 >> 2) + 1];
            short8 o;
            o[0] = (short)bf2u(a.x); o[1] = (short)bf2u(a.y);
            o[2] = (short)bf2u(a.z); o[3] = (short)bf2u(a.w);
            o[4] = (short)bf2u(b.x); o[5] = (short)bf2u(b.y);
            o[6] = (short)bf2u(b.z); o[7] = (short)bf2u(b.w);
            *(short8*)&s_pairb[row][c8] = o;
        }
    }
    __syncthreads();

    const uint4* qrow = (const uint4*)&s_qb[h][0];
    float d0 = 0.f, d1 = 0.f, d2 = 0.f, d3 = 0.f;

#define DOT_CHUNK(KV, u) do { \
        const uint4 Q = qrow[u]; \
        d0 = fmaf(bl16(KV.x), bl16(Q.x), fmaf(bh16(KV.x), bh16(Q.x), d0)); \
        d1 = fmaf(bl16(KV.y), bl16(Q.y), fmaf(bh16(KV.y), bh16(Q.y), d1)); \
        d2 = fmaf(bl16(KV.z), bl16(Q.z), fmaf(bh16(KV.z), bh16(Q.z), d2)); \
        d3 = fmaf(bl16(KV.w), bl16(Q.w), fmaf(bh16(KV.w), bh16(Q.w), d3)); \
    } while (0)

    uint4 kB0 = kp[2], kB1 = kp[3];
    asm volatile("" ::: "memory");
    DOT_CHUNK(kA0, 0); DOT_CHUNK(kA1, 1);
    kA0 = kp[4]; kA1 = kp[5];
    asm volatile("" ::: "memory");

    // --- waves 0,1: bias = P @ Wb via MFMA (covers kA latency)
    if (wave < 2) {
        const int lr = lane & 15;
        const int kg = lane >> 4;
        f32x4 cacc = {};
        const ushort* arow = &s_pairb[wave * 16 + lr][kg * 8];
        const ushort* brow = &s_wbTb[lr & 7][kg * 8];   // cols n>=8 read aliased rows, discarded
        #pragma unroll
        for (int ks = 0; ks < 4; ++ks) {
            const short8 af = *(const short8*)(arow + ks * 32);
            const short8 bf = *(const short8*)(brow + ks * 32);
            cacc = __builtin_amdgcn_mfma_f32_16x16x32_bf16(af, bf, cacc, 0, 0, 0);
        }
        if (lr < 8) {   // C: col h = lr, row j = wave*16 + kg*4 + r
            const int jj = wave * 16 + kg * 4;
            s_att[lr][jj + 0] = cacc[0];
            s_att[lr][jj + 1] = cacc[1];
            s_att[lr][jj + 2] = cacc[2];
            s_att[lr][jj + 3] = cacc[3];
        }
    }

    DOT_CHUNK(kB0, 2); DOT_CHUNK(kB1, 3);
    kB0 = kp[6]; kB1 = kp[7];
    asm volatile("" ::: "memory");
    DOT_CHUNK(kA0, 4); DOT_CHUNK(kA1, 5);
    DOT_CHUNK(kB0, 6); DOT_CHUNK(kB1, 7);
#undef DOT_CHUNK
    __syncthreads();   // MFMA bias in s_att visible to all

    // --- logit = w_L*(dot/8 + bias); in-place update of s_att[h][j]
    float logit = -1e9f;
    if (rowj >= 0) {
        const float dot = (d0 + d1) + (d2 + d3);
        logit = 0.70710678118f * (dot * 0.125f + s_att[h][j]);
    }
    s_att[h][j] = logit;
    __syncthreads();

    // --- out_scalar mapping + v-gather 2-deep pipeline (phase 0 covers softmax)
    const int slot = wave * 16 + (lane & 15);   // h = slot>>3, 16B chunk = slot&7
    const int jg = lane >> 4;                   // owns rows jg*8 .. jg*8+7
    const int hh = slot >> 3;
    const char* vbase = (const char*)vc;

#define VLOAD(u) (*(const uint4*)(vbase + (size_t)(s_nb[jg * 8 + (u)] < 0 ? 0 : s_nb[jg * 8 + (u)]) * 1024 + slot * 16))
#define VACC(V, a) do { \
        acc0 = fmaf(a, bl16(V.x), acc0); acc1 = fmaf(a, bh16(V.x), acc1); \
        acc2 = fmaf(a, bl16(V.y), acc2); acc3 = fmaf(a, bh16(V.y), acc3); \
        acc4 = fmaf(a, bl16(V.z), acc4); acc5 = fmaf(a, bh16(V.z), acc5); \
        acc6 = fmaf(a, bl16(V.w), acc6); acc7 = fmaf(a, bh16(V.w), acc7); \
    } while (0)

    uint4 vA0 = VLOAD(0), vA1 = VLOAD(1);
    asm volatile("" ::: "memory");

    // --- softmax over j: two register-lean float4 passes over s_att[h][*]
    {
        float mx = -1e30f;
        #pragma unroll
        for (int t = 0; t < 8; ++t) {
            const float4 w = *(const float4*)&s_att[h][t * 4];
            mx = fmaxf(mx, fmaxf(fmaxf(w.x, w.y), fmaxf(w.z, w.w)));
        }
        float s0 = 0.f, s1 = 0.f;
        #pragma unroll
        for (int t = 0; t < 8; ++t) {
            const float4 w = *(const float4*)&s_att[h][t * 4];
            s0 += __expf(w.x - mx) + __expf(w.z - mx);
            s1 += __expf(w.y - mx) + __expf(w.w - mx);
        }
        float aval = __expf(logit - mx) / (s0 + s1);
        if (rowj < 0) aval = 0.0f;
        s_att2[h][j] = aval;
    }
    __syncthreads();

    // --- att weights for out_scalar (float4 broadcast reads)
    const float4 w0 = *(const float4*)&s_att2[hh][jg * 8];
    const float4 w1 = *(const float4*)&s_att2[hh][jg * 8 + 4];

    float acc0 = 0.f, acc1 = 0.f, acc2 = 0.f, acc3 = 0.f;
    float acc4 = 0.f, acc5 = 0.f, acc6 = 0.f, acc7 = 0.f;

    uint4 vB0 = VLOAD(2), vB1 = VLOAD(3);
    asm volatile("" ::: "memory");
    VACC(vA0, w0.x); VACC(vA1, w0.y);
    vA0 = VLOAD(4); vA1 = VLOAD(5);
    asm volatile("" ::: "memory");
    VACC(vB0, w0.z); VACC(vB1, w0.w);
    vB0 = VLOAD(6); vB1 = VLOAD(7);
    asm volatile("" ::: "memory");

    // --- out_pair[h,c] -> cat[i, h*128+c]; covers the vA/vB latency
    {
        const int h2 = tid >> 5;
        const int c0 = (tid & 31) * 4;
        float4 aA = make_float4(0.f, 0.f, 0.f, 0.f);
        float4 aB = make_float4(0.f, 0.f, 0.f, 0.f);
        #pragma unroll
        for (int t = 0; t < 8; ++t) {
            const float4 aw = *(const float4*)&s_att2[h2][t * 4];
            const uint2 p0 = *(const uint2*)&s_pairb[t * 4 + 0][c0];
            const uint2 p1 = *(const uint2*)&s_pairb[t * 4 + 1][c0];
            const uint2 p2 = *(const uint2*)&s_pairb[t * 4 + 2][c0];
            const uint2 p3 = *(const uint2*)&s_pairb[t * 4 + 3][c0];
            aA.x = fmaf(aw.x, bl16(p0.x), aA.x); aA.y = fmaf(aw.x, bh16(p0.x), aA.y);
            aA.z = fmaf(aw.x, bl16(p0.y), aA.z); aA.w = fmaf(aw.x, bh16(p0.y), aA.w);
            aB.x = fmaf(aw.y, bl16(p1.x), aB.x); aB.y = fmaf(aw.y, bh16(p1.x), aB.y);
            aB.z = fmaf(aw.y, bl16(p1.y), aB.z); aB.w = fmaf(aw.y, bh16(p1.y), aB.w);
            aA.x = fmaf(aw.z, bl16(p2.x), aA.x); aA.y = fmaf(aw.z, bh16(p2.x), aA.y);
            aA.z = fmaf(aw.z, bl16(p2.y), aA.z); aA.w = fmaf(aw.z, bh16(p2.y), aA.w);
            aB.x = fmaf(aw.w, bl16(p3.x), aB.x); aB.y = fmaf(aw.w, bh16(p3.x), aB.y);
            aB.z = fmaf(aw.w, bl16(p3.y), aB.z); aB.w = fmaf(aw.w, bh16(p3.y), aB.w);
        }
        ushort4 o;
        o.x = bf2u(aA.x + aB.x); o.y = bf2u(aA.y + aB.y);
        o.z = bf2u(aA.z + aB.z); o.w = bf2u(aA.w + aB.w);
        *(ushort4*)&cat[(size_t)i * DCAT + h2 * CPD + c0] = o;
    }

    // --- out_scalar tail: consume remaining v, reduce, store
    VACC(vA0, w1.x); VACC(vA1, w1.y);
    VACC(vB0, w1.z); VACC(vB1, w1.w);
#undef VLOAD
#undef VACC
    acc0 += __shfl_xor(acc0, 16); acc0 += __shfl_xor(acc0, 32);
    acc1 += __shfl_xor(acc1, 16); acc1 += __shfl_xor(acc1, 32);
    acc2 += __shfl_xor(acc2, 16); acc2 += __shfl_xor(acc2, 32);
    acc3 += __shfl_xor(acc3, 16); acc3 += __shfl_xor(acc3, 32);
    acc4 += __shfl_xor(acc4, 16); acc4 += __shfl_xor(acc4, 32);
    acc5 += __shfl_xor(acc5, 16); acc5 += __shfl_xor(acc5, 32);
    acc6 += __shfl_xor(acc6, 16); acc6 += __shfl_xor(acc6, 32);
    acc7 += __shfl_xor(acc7, 16); acc7 += __shfl_xor(acc7, 32);
    if (jg == 0) {
        short8 o;
        o[0] = (short)bf2u(acc0); o[1] = (short)bf2u(acc1);
        o[2] = (short)bf2u(acc2); o[3] = (short)bf2u(acc3);
        o[4] = (short)bf2u(acc4); o[5] = (short)bf2u(acc5);
        o[6] = (short)bf2u(acc6); o[7] = (short)bf2u(acc7);
        char* dst = (char*)cat + ((size_t)i * DCAT + NH * CPD) * 2 + slot * 16;
        *(short8*)dst = o;
    }
}

extern "C" void kernel_launch(void* const* d_in, const int* in_sizes, int n_in,
                              void* d_out, int out_size, void* d_ws, size_t ws_size,
                              hipStream_t stream)
{
    const float* local  = (const float*)d_in[0];
    const float* pair   = (const float*)d_in[1];
    const int*   nbr    = (const int*)d_in[2];
    const float* w_qkv  = (const float*)d_in[4];
    const float* g_q    = (const float*)d_in[5];
    const float* b_q    = (const float*)d_in[6];
    const float* g_k    = (const float*)d_in[7];
    const float* b_k    = (const float*)d_in[8];
    const float* w_bias = (const float*)d_in[9];
    const float* w_out  = (const float*)d_in[10];
    const float* b_out  = (const float*)d_in[11];
    float* out = (float*)d_out;

    char* base = (char*)d_ws;
    ushort*         qkvb  = (ushort*)base;                         // [N,1536] bf16
    __hip_bfloat16* cat_b = (__hip_bfloat16*)base;                 // aliases qkvb after LN
    ushort*         lc    = (ushort*)(base + 100663296u);
    __hip_bfloat16* wqkvT = (__hip_bfloat16*)(base + 117440512u);
    __hip_bfloat16* woutT = (__hip_bfloat16*)(base + 119013376u);
    __hip_bfloat16* qc    = (__hip_bfloat16*)(base + 120586240u);
    __hip_bfloat16* kc    = (__hip_bfloat16*)(base + 137363456u);
    __hip_bfloat16* vc    = (__hip_bfloat16*)(base + 154140672u);

    cvt_bf16_kernel<<<(NTOK * CDIM / 4 + 255) / 256, 256, 0, stream>>>(
        (const float4*)local, (ushort4*)lc, NTOK * CDIM / 4);
    transpose_cvt<<<dim3(QKV_W / 32, CDIM / 32), 256, 0, stream>>>(w_qkv, wqkvT, CDIM, QKV_W);
    transpose_cvt<<<dim3(CDIM / 32, DCAT / 32), 256, 0, stream>>>(w_out, woutT, DCAT, CDIM);

    // 1) qkv = local @ w_qkv  -> bf16 output
    hipLaunchKernelGGL((gemm_bf16<false, true>), dim3(QKV_W / 128, NTOK / 128), dim3(256), 0, stream,
                       lc, (const ushort*)wqkvT, nullptr, (void*)qkvb, NTOK, QKV_W, CDIM);

    // 2) LN(q), LN(k) from bf16 qkv -> compact bf16 q/k/v
    ln_kernel<<<NTOK * NH / 4, 256, 0, stream>>>(qkvb, g_q, b_q, g_k, b_k, qc, kc, vc);

    // 3) fused neighbour attention -> cat (bf16, aliases dead qkv buffer)
    attn_kernel<<<NTOK, 256, 0, stream>>>(qc, kc, vc, pair, nbr, w_bias, cat_b);

    // 4) out = cat @ w_out + b_out  (fp32 output)
    hipLaunchKernelGGL((gemm_bf16<true, false>), dim3(CDIM / 128, NTOK / 128), dim3(256), 0, stream,
                       (const ushort*)cat_b, (const ushort*)woutT, b_out, (void*)out, NTOK, CDIM, DCAT);
}

// Round 11
// 341.185 us; speedup vs baseline: 7.0390x; 1.0329x over previous
//
#include <hip/hip_runtime.h>
#include <hip/hip_bf16.h>
#include <cstdint>

#define NTOK 16384
#define CDIM 512
#define KNB 32
#define CPD 128
#define NH 8
#define SD 64
#define QKV_W 1536   // H*3*S
#define DCAT 1536    // H*CP + H*S

typedef __attribute__((ext_vector_type(8))) short short8;
typedef __attribute__((ext_vector_type(4))) float f32x4;

__device__ inline float bl16(unsigned w) { return __uint_as_float(w << 16); }
__device__ inline float bh16(unsigned w) { return __uint_as_float(w & 0xffff0000u); }
__device__ inline float u16f(ushort u) { return __uint_as_float(((unsigned)u) << 16); }

__device__ inline ushort bf2u(float x) {
    __hip_bfloat16 b = __float2bfloat16(x);
    return *(const ushort*)&b;
}

__device__ inline void gload_lds16(const void* g, void* l) {
    __builtin_amdgcn_global_load_lds((const __attribute__((address_space(1))) void*)g,
                                     (__attribute__((address_space(3))) void*)l, 16, 0, 0);
}

// ---------------- elementwise fp32 -> bf16 convert (vectorized) ----------------
__global__ __launch_bounds__(256) void cvt_bf16_kernel(const float4* __restrict__ in,
                                                       ushort4* __restrict__ out, int n4)
{
    const int idx = blockIdx.x * 256 + threadIdx.x;
    if (idx < n4) {
        const float4 v = in[idx];
        ushort4 o;
        o.x = bf2u(v.x); o.y = bf2u(v.y); o.z = bf2u(v.z); o.w = bf2u(v.w);
        out[idx] = o;
    }
}

// ---------------- transpose + convert: in [R][Cc] fp32 -> out [Cc][R] bf16 ----------------
__global__ __launch_bounds__(256) void transpose_cvt(const float* __restrict__ in,
                                                     __hip_bfloat16* __restrict__ out,
                                                     int R, int Cc)
{
    __shared__ float t[32][33];
    const int c0 = blockIdx.x * 32, r0 = blockIdx.y * 32;
    const int tx = threadIdx.x & 31, ty = threadIdx.x >> 5;
    #pragma unroll
    for (int rr = ty; rr < 32; rr += 8)
        t[rr][tx] = in[(size_t)(r0 + rr) * Cc + c0 + tx];
    __syncthreads();
    #pragma unroll
    for (int rr = ty; rr < 32; rr += 8)
        out[(size_t)(c0 + rr) * R + r0 + tx] = __float2bfloat16(t[tx][rr]);
}

// ---------------- bf16 MFMA GEMM: C[M,N] = A[M,K](bf16) @ Bt[N,K](bf16)^T (+bias) -------
template<bool ADD_BIAS, bool OUT_BF16>
__global__ __launch_bounds__(256) void gemm_bf16(const ushort* __restrict__ A,
                                                 const ushort* __restrict__ Bt,
                                                 const float* __restrict__ bias,
                                                 void* __restrict__ Cv,
                                                 int M, int N, int K)
{
    __shared__ __align__(16) ushort Asl[128 * 32];
    __shared__ __align__(16) ushort Bsl[128 * 32];

    const int tid = threadIdx.x;
    const int wave = tid >> 6;
    const int lane = tid & 63;
    const int m0 = blockIdx.y * 128;
    const int n0 = blockIdx.x * 128;
    const int wr = wave >> 1, wc = wave & 1;

    f32x4 acc[4][4] = {};

    const int st_row_in_chunk = lane >> 2;
    const int st_bcol = (lane & 3) * 16;

    const int lr = lane & 15;
    const int kg = lane >> 4;

    for (int kt = 0; kt < K; kt += 32) {
        #pragma unroll
        for (int p = 0; p < 2; ++p) {
            const int chunk = wave * 2 + p;
            const int row = chunk * 16 + st_row_in_chunk;
            const char* asrc = (const char*)(A + (size_t)(m0 + row) * K + kt) + st_bcol;
            const char* bsrc = (const char*)(Bt + (size_t)(n0 + row) * K + kt) + st_bcol;
            gload_lds16(asrc, (char*)Asl + chunk * 1024);
            gload_lds16(bsrc, (char*)Bsl + chunk * 1024);
        }
        __syncthreads();

        short8 a[4], b[4];
        #pragma unroll
        for (int m = 0; m < 4; ++m)
            a[m] = *(const short8*)&Asl[(wr * 64 + m * 16 + lr) * 32 + kg * 8];
        #pragma unroll
        for (int n = 0; n < 4; ++n)
            b[n] = *(const short8*)&Bsl[(wc * 64 + n * 16 + lr) * 32 + kg * 8];
        #pragma unroll
        for (int m = 0; m < 4; ++m)
            #pragma unroll
            for (int n = 0; n < 4; ++n)
                acc[m][n] = __builtin_amdgcn_mfma_f32_16x16x32_bf16(a[m], b[n], acc[m][n], 0, 0, 0);
        __syncthreads();
    }

    #pragma unroll
    for (int m = 0; m < 4; ++m) {
        #pragma unroll
        for (int n = 0; n < 4; ++n) {
            const int col = n0 + wc * 64 + n * 16 + lr;
            const float bv = ADD_BIAS ? bias[col] : 0.0f;
            #pragma unroll
            for (int r = 0; r < 4; ++r) {
                const int row = m0 + wr * 64 + m * 16 + kg * 4 + r;
                if (OUT_BF16)
                    ((ushort*)Cv)[(size_t)row * N + col] = bf2u(acc[m][n][r] + bv);
                else
                    ((float*)Cv)[(size_t)row * N + col] = acc[m][n][r] + bv;
            }
        }
    }
}

// ---------------- LayerNorm q,k + compact bf16 q/k/v (bf16 qkv input) -------------
__global__ __launch_bounds__(256) void ln_kernel(const ushort* __restrict__ qkvb,
                                                 const float* __restrict__ g_q,
                                                 const float* __restrict__ b_q,
                                                 const float* __restrict__ g_k,
                                                 const float* __restrict__ b_k,
                                                 __hip_bfloat16* __restrict__ qc,
                                                 __hip_bfloat16* __restrict__ kc,
                                                 __hip_bfloat16* __restrict__ vc)
{
    const int gid = blockIdx.x * 4 + (threadIdx.x >> 6);   // i*8 + h
    const int lane = threadIdx.x & 63;

    const ushort* p = qkvb + (size_t)(gid >> 3) * QKV_W + (gid & 7) * 192;
    const float q = u16f(p[lane]);
    const float k = u16f(p[64 + lane]);
    const ushort v = p[128 + lane];

    float sq = q, sk = k;
    #pragma unroll
    for (int o = 1; o < 64; o <<= 1) { sq += __shfl_xor(sq, o); sk += __shfl_xor(sk, o); }
    const float mq = sq * (1.0f / 64.0f), mk = sk * (1.0f / 64.0f);
    const float dq = q - mq, dk = k - mk;
    float vq = dq * dq, vk = dk * dk;
    #pragma unroll
    for (int o = 1; o < 64; o <<= 1) { vq += __shfl_xor(vq, o); vk += __shfl_xor(vk, o); }
    const float iq = rsqrtf(vq * (1.0f / 64.0f) + 1e-5f);
    const float ik = rsqrtf(vk * (1.0f / 64.0f) + 1e-5f);

    const size_t o64 = (size_t)gid * 64 + lane;
    qc[o64] = __float2bfloat16(dq * iq * g_q[lane] + b_q[lane]);
    kc[o64] = __float2bfloat16(dk * ik * g_k[lane] + b_k[lane]);
    *(ushort*)&vc[o64] = v;
}

// ---------------- fused neighbour attention: one block per token i ----------------
__global__ __launch_bounds__(256) void attn_kernel(const __hip_bfloat16* __restrict__ qc,
                                                   const __hip_bfloat16* __restrict__ kc,
                                                   const __hip_bfloat16* __restrict__ vc,
                                                   const float* __restrict__ pair,
                                                   const int* __restrict__ nbr,
                                                   const float* __restrict__ w_bias,
                                                   __hip_bfloat16* __restrict__ cat)
{
    __shared__ __align__(16) ushort s_pairb[KNB][CPD + 8];  // 8.5 KB, row 272 B
    __shared__ __align__(16) ushort s_wbTb[NH][CPD + 8];    // 2.2 KB
    __shared__ __align__(16) ushort s_qb[NH][SD + 8];       // 1.2 KB
    __shared__ __align__(16) float s_att[NH][KNB + 4];      // bias -> logits (in place)
    __shared__ __align__(16) float s_att2[NH][KNB + 4];     // softmax weights
    __shared__ int s_nb[KNB];

    const int i = blockIdx.x;
    const int tid = threadIdx.x;
    const int j = tid >> 3;
    const int h = tid & 7;
    const int wave = tid >> 6;
    const int lane = tid & 63;

    // --- k-gather 2-deep pipeline, phase 0 issued pre-barrier (16 regs peak)
    const int rowj = nbr[i * KNB + j];
    const int rk = rowj < 0 ? 0 : rowj;
    const uint4* kp = (const uint4*)(kc + ((size_t)rk * NH + h) * SD);
    uint4 kA0 = kp[0], kA1 = kp[1];

    // --- LDS staging
    if (tid < KNB) s_nb[tid] = nbr[i * KNB + tid];
    if (tid < 64) {   // q already bf16: straight uint4 copy
        const uint4 qw = ((const uint4*)(qc + (size_t)i * 512))[tid];
        *(uint4*)&s_qb[tid >> 3][(tid & 7) * 8] = qw;
    }
    {   // w_bias [128][8] fp32 -> s_wbTb[h][c] bf16
        const float4 w4 = ((const float4*)w_bias)[tid];
        const int c = tid >> 1;
        const int h0 = (tid & 1) * 4;
        s_wbTb[h0 + 0][c] = bf2u(w4.x);
        s_wbTb[h0 + 1][c] = bf2u(w4.y);
        s_wbTb[h0 + 2][c] = bf2u(w4.z);
        s_wbTb[h0 + 3][c] = bf2u(w4.w);
    }
    {   // pair tile fp32 -> bf16 LDS; NONTEMPORAL: pair is single-use, keep LLC for k/v
        const f32x4* pr = (const f32x4*)(pair + (size_t)i * KNB * CPD);
        #pragma unroll
        for (int t2 = 0; t2 < 2; ++t2) {
            const int ch = t2 * 256 + tid;
            const int row = ch >> 4;
            const int c8 = (ch & 15) * 8;
            const f32x4 a = __builtin_nontemporal_load(pr + row * 32 + (c8 >> 2));
            const f32x4 b = __builtin_nontemporal_load(pr + row * 32 + (c8 >> 2) + 1);
            short8 o;
            o[0] = (short)bf2u(a[0]); o[1] = (short)bf2u(a[1]);
            o[2] = (short)bf2u(a[2]); o[3] = (short)bf2u(a[3]);
            o[4] = (short)bf2u(b[0]); o[5] = (short)bf2u(b[1]);
            o[6] = (short)bf2u(b[2]); o[7] = (short)bf2u(b[3]);
            *(short8*)&s_pairb[row][c8] = o;
        }
    }
    __syncthreads();

    const uint4* qrow = (const uint4*)&s_qb[h][0];
    float d0 = 0.f, d1 = 0.f, d2 = 0.f, d3 = 0.f;

#define DOT_CHUNK(KV, u) do { \
        const uint4 Q = qrow[u]; \
        d0 = fmaf(bl16(KV.x), bl16(Q.x), fmaf(bh16(KV.x), bh16(Q.x), d0)); \
        d1 = fmaf(bl16(KV.y), bl16(Q.y), fmaf(bh16(KV.y), bh16(Q.y), d1)); \
        d2 = fmaf(bl16(KV.z), bl16(Q.z), fmaf(bh16(KV.z), bh16(Q.z), d2)); \
        d3 = fmaf(bl16(KV.w), bl16(Q.w), fmaf(bh16(KV.w), bh16(Q.w), d3)); \
    } while (0)

    uint4 kB0 = kp[2], kB1 = kp[3];
    asm volatile("" ::: "memory");
    DOT_CHUNK(kA0, 0); DOT_CHUNK(kA1, 1);
    kA0 = kp[4]; kA1 = kp[5];
    asm volatile("" ::: "memory");

    // --- waves 0,1: bias = P @ Wb via MFMA (covers kA latency)
    if (wave < 2) {
        const int lr = lane & 15;
        const int kg = lane >> 4;
        f32x4 cacc = {};
        const ushort* arow = &s_pairb[wave * 16 + lr][kg * 8];
        const ushort* brow = &s_wbTb[lr & 7][kg * 8];   // cols n>=8 read aliased rows, discarded
        #pragma unroll
        for (int ks = 0; ks < 4; ++ks) {
            const short8 af = *(const short8*)(arow + ks * 32);
            const short8 bf = *(const short8*)(brow + ks * 32);
            cacc = __builtin_amdgcn_mfma_f32_16x16x32_bf16(af, bf, cacc, 0, 0, 0);
        }
        if (lr < 8) {   // C: col h = lr, row j = wave*16 + kg*4 + r
            const int jj = wave * 16 + kg * 4;
            s_att[lr][jj + 0] = cacc[0];
            s_att[lr][jj + 1] = cacc[1];
            s_att[lr][jj + 2] = cacc[2];
            s_att[lr][jj + 3] = cacc[3];
        }
    }

    DOT_CHUNK(kB0, 2); DOT_CHUNK(kB1, 3);
    kB0 = kp[6]; kB1 = kp[7];
    asm volatile("" ::: "memory");
    DOT_CHUNK(kA0, 4); DOT_CHUNK(kA1, 5);
    DOT_CHUNK(kB0, 6); DOT_CHUNK(kB1, 7);
#undef DOT_CHUNK
    __syncthreads();   // MFMA bias in s_att visible to all

    // --- logit = w_L*(dot/8 + bias); in-place update of s_att[h][j]
    float logit = -1e9f;
    if (rowj >= 0) {
        const float dot = (d0 + d1) + (d2 + d3);
        logit = 0.70710678118f * (dot * 0.125f + s_att[h][j]);
    }
    s_att[h][j] = logit;
    __syncthreads();

    // --- out_scalar mapping + v-gather 2-deep pipeline (phase 0 covers softmax)
    const int slot = wave * 16 + (lane & 15);   // h = slot>>3, 16B chunk = slot&7
    const int jg = lane >> 4;                   // owns rows jg*8 .. jg*8+7
    const int hh = slot >> 3;
    const char* vbase = (const char*)vc;

#define VLOAD(u) (*(const uint4*)(vbase + (size_t)(s_nb[jg * 8 + (u)] < 0 ? 0 : s_nb[jg * 8 + (u)]) * 1024 + slot * 16))
#define VACC(V, a) do { \
        acc0 = fmaf(a, bl16(V.x), acc0); acc1 = fmaf(a, bh16(V.x), acc1); \
        acc2 = fmaf(a, bl16(V.y), acc2); acc3 = fmaf(a, bh16(V.y), acc3); \
        acc4 = fmaf(a, bl16(V.z), acc4); acc5 = fmaf(a, bh16(V.z), acc5); \
        acc6 = fmaf(a, bl16(V.w), acc6); acc7 = fmaf(a, bh16(V.w), acc7); \
    } while (0)

    uint4 vA0 = VLOAD(0), vA1 = VLOAD(1);
    asm volatile("" ::: "memory");

    // --- softmax over j: two register-lean float4 passes over s_att[h][*]
    {
        float mx = -1e30f;
        #pragma unroll
        for (int t = 0; t < 8; ++t) {
            const float4 w = *(const float4*)&s_att[h][t * 4];
            mx = fmaxf(mx, fmaxf(fmaxf(w.x, w.y), fmaxf(w.z, w.w)));
        }
        float s0 = 0.f, s1 = 0.f;
        #pragma unroll
        for (int t = 0; t < 8; ++t) {
            const float4 w = *(const float4*)&s_att[h][t * 4];
            s0 += __expf(w.x - mx) + __expf(w.z - mx);
            s1 += __expf(w.y - mx) + __expf(w.w - mx);
        }
        float aval = __expf(logit - mx) / (s0 + s1);
        if (rowj < 0) aval = 0.0f;
        s_att2[h][j] = aval;
    }
    __syncthreads();

    // --- att weights for out_scalar (float4 broadcast reads)
    const float4 w0 = *(const float4*)&s_att2[hh][jg * 8];
    const float4 w1 = *(const float4*)&s_att2[hh][jg * 8 + 4];

    float acc0 = 0.f, acc1 = 0.f, acc2 = 0.f, acc3 = 0.f;
    float acc4 = 0.f, acc5 = 0.f, acc6 = 0.f, acc7 = 0.f;

    uint4 vB0 = VLOAD(2), vB1 = VLOAD(3);
    asm volatile("" ::: "memory");
    VACC(vA0, w0.x); VACC(vA1, w0.y);
    vA0 = VLOAD(4); vA1 = VLOAD(5);
    asm volatile("" ::: "memory");
    VACC(vB0, w0.z); VACC(vB1, w0.w);
    vB0 = VLOAD(6); vB1 = VLOAD(7);
    asm volatile("" ::: "memory");

    // --- out_pair[h,c] -> cat[i, h*128+c]; covers the vA/vB latency
    {
        const int h2 = tid >> 5;
        const int c0 = (tid & 31) * 4;
        float4 aA = make_float4(0.f, 0.f, 0.f, 0.f);
        float4 aB = make_float4(0.f, 0.f, 0.f, 0.f);
        #pragma unroll
        for (int t = 0; t < 8; ++t) {
            const float4 aw = *(const float4*)&s_att2[h2][t * 4];
            const uint2 p0 = *(const uint2*)&s_pairb[t * 4 + 0][c0];
            const uint2 p1 = *(const uint2*)&s_pairb[t * 4 + 1][c0];
            const uint2 p2 = *(const uint2*)&s_pairb[t * 4 + 2][c0];
            const uint2 p3 = *(const uint2*)&s_pairb[t * 4 + 3][c0];
            aA.x = fmaf(aw.x, bl16(p0.x), aA.x); aA.y = fmaf(aw.x, bh16(p0.x), aA.y);
            aA.z = fmaf(aw.x, bl16(p0.y), aA.z); aA.w = fmaf(aw.x, bh16(p0.y), aA.w);
            aB.x = fmaf(aw.y, bl16(p1.x), aB.x); aB.y = fmaf(aw.y, bh16(p1.x), aB.y);
            aB.z = fmaf(aw.y, bl16(p1.y), aB.z); aB.w = fmaf(aw.y, bh16(p1.y), aB.w);
            aA.x = fmaf(aw.z, bl16(p2.x), aA.x); aA.y = fmaf(aw.z, bh16(p2.x), aA.y);
            aA.z = fmaf(aw.z, bl16(p2.y), aA.z); aA.w = fmaf(aw.z, bh16(p2.y), aA.w);
            aB.x = fmaf(aw.w, bl16(p3.x), aB.x); aB.y = fmaf(aw.w, bh16(p3.x), aB.y);
            aB.z = fmaf(aw.w, bl16(p3.y), aB.z); aB.w = fmaf(aw.w, bh16(p3.y), aB.w);
        }
        ushort4 o;
        o.x = bf2u(aA.x + aB.x); o.y = bf2u(aA.y + aB.y);
        o.z = bf2u(aA.z + aB.z); o.w = bf2u(aA.w + aB.w);
        *(ushort4*)&cat[(size_t)i * DCAT + h2 * CPD + c0] = o;
    }

    // --- out_scalar tail: consume remaining v, reduce, store
    VACC(vA0, w1.x); VACC(vA1, w1.y);
    VACC(vB0, w1.z); VACC(vB1, w1.w);
#undef VLOAD
#undef VACC
    acc0 += __shfl_xor(acc0, 16); acc0 += __shfl_xor(acc0, 32);
    acc1 += __shfl_xor(acc1, 16); acc1 += __shfl_xor(acc1, 32);
    acc2 += __shfl_xor(acc2, 16); acc2 += __shfl_xor(acc2, 32);
    acc3 += __shfl_xor(acc3, 16); acc3 += __shfl_xor(acc3, 32);
    acc4 += __shfl_xor(acc4, 16); acc4 += __shfl_xor(acc4, 32);
    acc5 += __shfl_xor(acc5, 16); acc5 += __shfl_xor(acc5, 32);
    acc6 += __shfl_xor(acc6, 16); acc6 += __shfl_xor(acc6, 32);
    acc7 += __shfl_xor(acc7, 16); acc7 += __shfl_xor(acc7, 32);
    if (jg == 0) {
        short8 o;
        o[0] = (short)bf2u(acc0); o[1] = (short)bf2u(acc1);
        o[2] = (short)bf2u(acc2); o[3] = (short)bf2u(acc3);
        o[4] = (short)bf2u(acc4); o[5] = (short)bf2u(acc5);
        o[6] = (short)bf2u(acc6); o[7] = (short)bf2u(acc7);
        char* dst = (char*)cat + ((size_t)i * DCAT + NH * CPD) * 2 + slot * 16;
        *(short8*)dst = o;
    }
}

extern "C" void kernel_launch(void* const* d_in, const int* in_sizes, int n_in,
                              void* d_out, int out_size, void* d_ws, size_t ws_size,
                              hipStream_t stream)
{
    const float* local  = (const float*)d_in[0];
    const float* pair   = (const float*)d_in[1];
    const int*   nbr    = (const int*)d_in[2];
    const float* w_qkv  = (const float*)d_in[4];
    const float* g_q    = (const float*)d_in[5];
    const float* b_q    = (const float*)d_in[6];
    const float* g_k    = (const float*)d_in[7];
    const float* b_k    = (const float*)d_in[8];
    const float* w_bias = (const float*)d_in[9];
    const float* w_out  = (const float*)d_in[10];
    const float* b_out  = (const float*)d_in[11];
    float* out = (float*)d_out;

    char* base = (char*)d_ws;
    ushort*         qkvb  = (ushort*)base;                         // [N,1536] bf16
    __hip_bfloat16* cat_b = (__hip_bfloat16*)base;                 // aliases qkvb after LN
    ushort*         lc    = (ushort*)(base + 100663296u);
    __hip_bfloat16* wqkvT = (__hip_bfloat16*)(base + 117440512u);
    __hip_bfloat16* woutT = (__hip_bfloat16*)(base + 119013376u);
    __hip_bfloat16* qc    = (__hip_bfloat16*)(base + 120586240u);
    __hip_bfloat16* kc    = (__hip_bfloat16*)(base + 137363456u);
    __hip_bfloat16* vc    = (__hip_bfloat16*)(base + 154140672u);

    cvt_bf16_kernel<<<(NTOK * CDIM / 4 + 255) / 256, 256, 0, stream>>>(
        (const float4*)local, (ushort4*)lc, NTOK * CDIM / 4);
    transpose_cvt<<<dim3(QKV_W / 32, CDIM / 32), 256, 0, stream>>>(w_qkv, wqkvT, CDIM, QKV_W);
    transpose_cvt<<<dim3(CDIM / 32, DCAT / 32), 256, 0, stream>>>(w_out, woutT, DCAT, CDIM);

    // 1) qkv = local @ w_qkv  -> bf16 output
    hipLaunchKernelGGL((gemm_bf16<false, true>), dim3(QKV_W / 128, NTOK / 128), dim3(256), 0, stream,
                       lc, (const ushort*)wqkvT, nullptr, (void*)qkvb, NTOK, QKV_W, CDIM);

    // 2) LN(q), LN(k) from bf16 qkv -> compact bf16 q/k/v
    ln_kernel<<<NTOK * NH / 4, 256, 0, stream>>>(qkvb, g_q, b_q, g_k, b_k, qc, kc, vc);

    // 3) fused neighbour attention -> cat (bf16, aliases dead qkv buffer)
    attn_kernel<<<NTOK, 256, 0, stream>>>(qc, kc, vc, pair, nbr, w_bias, cat_b);

    // 4) out = cat @ w_out + b_out  (fp32 output)
    hipLaunchKernelGGL((gemm_bf16<true, false>), dim3(CDIM / 128, NTOK / 128), dim3(256), 0, stream,
                       (const ushort*)cat_b, (const ushort*)woutT, b_out, (void*)out, NTOK, CDIM, DCAT);
}

// Round 12
// 333.880 us; speedup vs baseline: 7.1930x; 1.0219x over previous
//
#include <hip/hip_runtime.h>
#include <hip/hip_bf16.h>
#include <cstdint>

#define NTOK 16384
#define CDIM 512
#define KNB 32
#define CPD 128
#define NH 8
#define SD 64
#define QKV_W 1536   // H*3*S
#define DCAT 1536    // H*CP + H*S

typedef __attribute__((ext_vector_type(8))) short short8;
typedef __attribute__((ext_vector_type(4))) float f32x4;

__device__ inline float bl16(unsigned w) { return __uint_as_float(w << 16); }
__device__ inline float bh16(unsigned w) { return __uint_as_float(w & 0xffff0000u); }
__device__ inline float u16f(ushort u) { return __uint_as_float(((unsigned)u) << 16); }

__device__ inline ushort bf2u(float x) {
    __hip_bfloat16 b = __float2bfloat16(x);
    return *(const ushort*)&b;
}

__device__ inline void gload_lds16(const void* g, void* l) {
    __builtin_amdgcn_global_load_lds((const __attribute__((address_space(1))) void*)g,
                                     (__attribute__((address_space(3))) void*)l, 16, 0, 0);
}

// ---------------- elementwise fp32 -> bf16 convert (vectorized) ----------------
__global__ __launch_bounds__(256) void cvt_bf16_kernel(const float4* __restrict__ in,
                                                       ushort4* __restrict__ out, int n4)
{
    const int idx = blockIdx.x * 256 + threadIdx.x;
    if (idx < n4) {
        const float4 v = in[idx];
        ushort4 o;
        o.x = bf2u(v.x); o.y = bf2u(v.y); o.z = bf2u(v.z); o.w = bf2u(v.w);
        out[idx] = o;
    }
}

// ---------------- transpose + convert: in [R][Cc] fp32 -> out [Cc][R] bf16 ----------------
__global__ __launch_bounds__(256) void transpose_cvt(const float* __restrict__ in,
                                                     __hip_bfloat16* __restrict__ out,
                                                     int R, int Cc)
{
    __shared__ float t[32][33];
    const int c0 = blockIdx.x * 32, r0 = blockIdx.y * 32;
    const int tx = threadIdx.x & 31, ty = threadIdx.x >> 5;
    #pragma unroll
    for (int rr = ty; rr < 32; rr += 8)
        t[rr][tx] = in[(size_t)(r0 + rr) * Cc + c0 + tx];
    __syncthreads();
    #pragma unroll
    for (int rr = ty; rr < 32; rr += 8)
        out[(size_t)(c0 + rr) * R + r0 + tx] = __float2bfloat16(t[tx][rr]);
}

// ---------------- bf16 MFMA GEMM: C[M,N] = A[M,K](bf16) @ Bt[N,K](bf16)^T (+bias) -------
// XCD-aware tile remap: blocks sharing an A row-panel run consecutively on ONE XCD
// so the panel stays hot in that XCD's 4 MB L2 (HW round-robins linear wgid % 8).
template<bool ADD_BIAS, bool OUT_BF16>
__global__ __launch_bounds__(256) void gemm_bf16(const ushort* __restrict__ A,
                                                 const ushort* __restrict__ Bt,
                                                 const float* __restrict__ bias,
                                                 void* __restrict__ Cv,
                                                 int M, int N, int K)
{
    __shared__ __align__(16) ushort Asl[128 * 32];
    __shared__ __align__(16) ushort Bsl[128 * 32];

    const int tid = threadIdx.x;
    const int wave = tid >> 6;
    const int lane = tid & 63;

    // --- XCD swizzle (gridDim.x * gridDim.y assumed multiple of 8, gridDim.y mult of 8)
    const int L = blockIdx.y * gridDim.x + blockIdx.x;   // HW dispatch order (x fastest)
    const int xcd = L & 7;
    const int slot = L >> 3;
    const int ypx = gridDim.y >> 3;                      // y-panels per XCD
    const int tileY = xcd * ypx + slot / gridDim.x;
    const int tileX = slot % gridDim.x;
    const int m0 = tileY * 128;
    const int n0 = tileX * 128;

    const int wr = wave >> 1, wc = wave & 1;

    f32x4 acc[4][4] = {};

    const int st_row_in_chunk = lane >> 2;
    const int st_bcol = (lane & 3) * 16;

    const int lr = lane & 15;
    const int kg = lane >> 4;

    for (int kt = 0; kt < K; kt += 32) {
        #pragma unroll
        for (int p = 0; p < 2; ++p) {
            const int chunk = wave * 2 + p;
            const int row = chunk * 16 + st_row_in_chunk;
            const char* asrc = (const char*)(A + (size_t)(m0 + row) * K + kt) + st_bcol;
            const char* bsrc = (const char*)(Bt + (size_t)(n0 + row) * K + kt) + st_bcol;
            gload_lds16(asrc, (char*)Asl + chunk * 1024);
            gload_lds16(bsrc, (char*)Bsl + chunk * 1024);
        }
        __syncthreads();

        short8 a[4], b[4];
        #pragma unroll
        for (int m = 0; m < 4; ++m)
            a[m] = *(const short8*)&Asl[(wr * 64 + m * 16 + lr) * 32 + kg * 8];
        #pragma unroll
        for (int n = 0; n < 4; ++n)
            b[n] = *(const short8*)&Bsl[(wc * 64 + n * 16 + lr) * 32 + kg * 8];
        #pragma unroll
        for (int m = 0; m < 4; ++m)
            #pragma unroll
            for (int n = 0; n < 4; ++n)
                acc[m][n] = __builtin_amdgcn_mfma_f32_16x16x32_bf16(a[m], b[n], acc[m][n], 0, 0, 0);
        __syncthreads();
    }

    #pragma unroll
    for (int m = 0; m < 4; ++m) {
        #pragma unroll
        for (int n = 0; n < 4; ++n) {
            const int col = n0 + wc * 64 + n * 16 + lr;
            const float bv = ADD_BIAS ? bias[col] : 0.0f;
            #pragma unroll
            for (int r = 0; r < 4; ++r) {
                const int row = m0 + wr * 64 + m * 16 + kg * 4 + r;
                if (OUT_BF16)
                    ((ushort*)Cv)[(size_t)row * N + col] = bf2u(acc[m][n][r] + bv);
                else
                    ((float*)Cv)[(size_t)row * N + col] = acc[m][n][r] + bv;
            }
        }
    }
}

// ---------------- LayerNorm q,k + compact bf16 q/k/v (bf16 qkv input) -------------
__global__ __launch_bounds__(256) void ln_kernel(const ushort* __restrict__ qkvb,
                                                 const float* __restrict__ g_q,
                                                 const float* __restrict__ b_q,
                                                 const float* __restrict__ g_k,
                                                 const float* __restrict__ b_k,
                                                 __hip_bfloat16* __restrict__ qc,
                                                 __hip_bfloat16* __restrict__ kc,
                                                 __hip_bfloat16* __restrict__ vc)
{
    const int gid = blockIdx.x * 4 + (threadIdx.x >> 6);   // i*8 + h
    const int lane = threadIdx.x & 63;

    const ushort* p = qkvb + (size_t)(gid >> 3) * QKV_W + (gid & 7) * 192;
    const float q = u16f(p[lane]);
    const float k = u16f(p[64 + lane]);
    const ushort v = p[128 + lane];

    float sq = q, sk = k;
    #pragma unroll
    for (int o = 1; o < 64; o <<= 1) { sq += __shfl_xor(sq, o); sk += __shfl_xor(sk, o); }
    const float mq = sq * (1.0f / 64.0f), mk = sk * (1.0f / 64.0f);
    const float dq = q - mq, dk = k - mk;
    float vq = dq * dq, vk = dk * dk;
    #pragma unroll
    for (int o = 1; o < 64; o <<= 1) { vq += __shfl_xor(vq, o); vk += __shfl_xor(vk, o); }
    const float iq = rsqrtf(vq * (1.0f / 64.0f) + 1e-5f);
    const float ik = rsqrtf(vk * (1.0f / 64.0f) + 1e-5f);

    const size_t o64 = (size_t)gid * 64 + lane;
    qc[o64] = __float2bfloat16(dq * iq * g_q[lane] + b_q[lane]);
    kc[o64] = __float2bfloat16(dk * ik * g_k[lane] + b_k[lane]);
    *(ushort*)&vc[o64] = v;
}

// ---------------- fused neighbour attention: one block per token i ----------------
__global__ __launch_bounds__(256) void attn_kernel(const __hip_bfloat16* __restrict__ qc,
                                                   const __hip_bfloat16* __restrict__ kc,
                                                   const __hip_bfloat16* __restrict__ vc,
                                                   const float* __restrict__ pair,
                                                   const int* __restrict__ nbr,
                                                   const float* __restrict__ w_bias,
                                                   __hip_bfloat16* __restrict__ cat)
{
    __shared__ __align__(16) ushort s_pairb[KNB][CPD + 8];  // 8.5 KB, row 272 B
    __shared__ __align__(16) ushort s_wbTb[NH][CPD + 8];    // 2.2 KB
    __shared__ __align__(16) ushort s_qb[NH][SD + 8];       // 1.2 KB
    __shared__ __align__(16) float s_att[NH][KNB + 4];      // bias -> logits (in place)
    __shared__ __align__(16) float s_att2[NH][KNB + 4];     // softmax weights
    __shared__ int s_nb[KNB];

    const int i = blockIdx.x;
    const int tid = threadIdx.x;
    const int j = tid >> 3;
    const int h = tid & 7;
    const int wave = tid >> 6;
    const int lane = tid & 63;

    // --- k-gather 2-deep pipeline, phase 0 issued pre-barrier (16 regs peak)
    const int rowj = nbr[i * KNB + j];
    const int rk = rowj < 0 ? 0 : rowj;
    const uint4* kp = (const uint4*)(kc + ((size_t)rk * NH + h) * SD);
    uint4 kA0 = kp[0], kA1 = kp[1];

    // --- LDS staging
    if (tid < KNB) s_nb[tid] = nbr[i * KNB + tid];
    if (tid < 64) {   // q already bf16: straight uint4 copy
        const uint4 qw = ((const uint4*)(qc + (size_t)i * 512))[tid];
        *(uint4*)&s_qb[tid >> 3][(tid & 7) * 8] = qw;
    }
    {   // w_bias [128][8] fp32 -> s_wbTb[h][c] bf16
        const float4 w4 = ((const float4*)w_bias)[tid];
        const int c = tid >> 1;
        const int h0 = (tid & 1) * 4;
        s_wbTb[h0 + 0][c] = bf2u(w4.x);
        s_wbTb[h0 + 1][c] = bf2u(w4.y);
        s_wbTb[h0 + 2][c] = bf2u(w4.z);
        s_wbTb[h0 + 3][c] = bf2u(w4.w);
    }
    {   // pair tile fp32 -> bf16 LDS; NONTEMPORAL: pair is single-use
        const f32x4* pr = (const f32x4*)(pair + (size_t)i * KNB * CPD);
        #pragma unroll
        for (int t2 = 0; t2 < 2; ++t2) {
            const int ch = t2 * 256 + tid;
            const int row = ch >> 4;
            const int c8 = (ch & 15) * 8;
            const f32x4 a = __builtin_nontemporal_load(pr + row * 32 + (c8 >> 2));
            const f32x4 b = __builtin_nontemporal_load(pr + row * 32 + (c8 >> 2) + 1);
            short8 o;
            o[0] = (short)bf2u(a[0]); o[1] = (short)bf2u(a[1]);
            o[2] = (short)bf2u(a[2]); o[3] = (short)bf2u(a[3]);
            o[4] = (short)bf2u(b[0]); o[5] = (short)bf2u(b[1]);
            o[6] = (short)bf2u(b[2]); o[7] = (short)bf2u(b[3]);
            *(short8*)&s_pairb[row][c8] = o;
        }
    }
    __syncthreads();

    const uint4* qrow = (const uint4*)&s_qb[h][0];
    float d0 = 0.f, d1 = 0.f, d2 = 0.f, d3 = 0.f;

#define DOT_CHUNK(KV, u) do { \
        const uint4 Q = qrow[u]; \
        d0 = fmaf(bl16(KV.x), bl16(Q.x), fmaf(bh16(KV.x), bh16(Q.x), d0)); \
        d1 = fmaf(bl16(KV.y), bl16(Q.y), fmaf(bh16(KV.y), bh16(Q.y), d1)); \
        d2 = fmaf(bl16(KV.z), bl16(Q.z), fmaf(bh16(KV.z), bh16(Q.z), d2)); \
        d3 = fmaf(bl16(KV.w), bl16(Q.w), fmaf(bh16(KV.w), bh16(Q.w), d3)); \
    } while (0)

    uint4 kB0 = kp[2], kB1 = kp[3];
    asm volatile("" ::: "memory");
    DOT_CHUNK(kA0, 0); DOT_CHUNK(kA1, 1);
    kA0 = kp[4]; kA1 = kp[5];
    asm volatile("" ::: "memory");

    // --- waves 0,1: bias = P @ Wb via MFMA (covers kA latency)
    if (wave < 2) {
        const int lr = lane & 15;
        const int kg = lane >> 4;
        f32x4 cacc = {};
        const ushort* arow = &s_pairb[wave * 16 + lr][kg * 8];
        const ushort* brow = &s_wbTb[lr & 7][kg * 8];   // cols n>=8 read aliased rows, discarded
        #pragma unroll
        for (int ks = 0; ks < 4; ++ks) {
            const short8 af = *(const short8*)(arow + ks * 32);
            const short8 bf = *(const short8*)(brow + ks * 32);
            cacc = __builtin_amdgcn_mfma_f32_16x16x32_bf16(af, bf, cacc, 0, 0, 0);
        }
        if (lr < 8) {   // C: col h = lr, row j = wave*16 + kg*4 + r
            const int jj = wave * 16 + kg * 4;
            s_att[lr][jj + 0] = cacc[0];
            s_att[lr][jj + 1] = cacc[1];
            s_att[lr][jj + 2] = cacc[2];
            s_att[lr][jj + 3] = cacc[3];
        }
    }

    DOT_CHUNK(kB0, 2); DOT_CHUNK(kB1, 3);
    kB0 = kp[6]; kB1 = kp[7];
    asm volatile("" ::: "memory");
    DOT_CHUNK(kA0, 4); DOT_CHUNK(kA1, 5);
    DOT_CHUNK(kB0, 6); DOT_CHUNK(kB1, 7);
#undef DOT_CHUNK
    __syncthreads();   // MFMA bias in s_att visible to all

    // --- logit = w_L*(dot/8 + bias); in-place update of s_att[h][j]
    float logit = -1e9f;
    if (rowj >= 0) {
        const float dot = (d0 + d1) + (d2 + d3);
        logit = 0.70710678118f * (dot * 0.125f + s_att[h][j]);
    }
    s_att[h][j] = logit;
    __syncthreads();

    // --- out_scalar mapping + v-gather 2-deep pipeline (phase 0 covers softmax)
    const int slot = wave * 16 + (lane & 15);   // h = slot>>3, 16B chunk = slot&7
    const int jg = lane >> 4;                   // owns rows jg*8 .. jg*8+7
    const int hh = slot >> 3;
    const char* vbase = (const char*)vc;

#define VLOAD(u) (*(const uint4*)(vbase + (size_t)(s_nb[jg * 8 + (u)] < 0 ? 0 : s_nb[jg * 8 + (u)]) * 1024 + slot * 16))
#define VACC(V, a) do { \
        acc0 = fmaf(a, bl16(V.x), acc0); acc1 = fmaf(a, bh16(V.x), acc1); \
        acc2 = fmaf(a, bl16(V.y), acc2); acc3 = fmaf(a, bh16(V.y), acc3); \
        acc4 = fmaf(a, bl16(V.z), acc4); acc5 = fmaf(a, bh16(V.z), acc5); \
        acc6 = fmaf(a, bl16(V.w), acc6); acc7 = fmaf(a, bh16(V.w), acc7); \
    } while (0)

    uint4 vA0 = VLOAD(0), vA1 = VLOAD(1);
    asm volatile("" ::: "memory");

    // --- softmax over j: two register-lean float4 passes over s_att[h][*]
    {
        float mx = -1e30f;
        #pragma unroll
        for (int t = 0; t < 8; ++t) {
            const float4 w = *(const float4*)&s_att[h][t * 4];
            mx = fmaxf(mx, fmaxf(fmaxf(w.x, w.y), fmaxf(w.z, w.w)));
        }
        float s0 = 0.f, s1 = 0.f;
        #pragma unroll
        for (int t = 0; t < 8; ++t) {
            const float4 w = *(const float4*)&s_att[h][t * 4];
            s0 += __expf(w.x - mx) + __expf(w.z - mx);
            s1 += __expf(w.y - mx) + __expf(w.w - mx);
        }
        float aval = __expf(logit - mx) / (s0 + s1);
        if (rowj < 0) aval = 0.0f;
        s_att2[h][j] = aval;
    }
    __syncthreads();

    // --- att weights for out_scalar (float4 broadcast reads)
    const float4 w0 = *(const float4*)&s_att2[hh][jg * 8];
    const float4 w1 = *(const float4*)&s_att2[hh][jg * 8 + 4];

    float acc0 = 0.f, acc1 = 0.f, acc2 = 0.f, acc3 = 0.f;
    float acc4 = 0.f, acc5 = 0.f, acc6 = 0.f, acc7 = 0.f;

    uint4 vB0 = VLOAD(2), vB1 = VLOAD(3);
    asm volatile("" ::: "memory");
    VACC(vA0, w0.x); VACC(vA1, w0.y);
    vA0 = VLOAD(4); vA1 = VLOAD(5);
    asm volatile("" ::: "memory");
    VACC(vB0, w0.z); VACC(vB1, w0.w);
    vB0 = VLOAD(6); vB1 = VLOAD(7);
    asm volatile("" ::: "memory");

    // --- out_pair[h,c] -> cat[i, h*128+c]; covers the vA/vB latency
    {
        const int h2 = tid >> 5;
        const int c0 = (tid & 31) * 4;
        float4 aA = make_float4(0.f, 0.f, 0.f, 0.f);
        float4 aB = make_float4(0.f, 0.f, 0.f, 0.f);
        #pragma unroll
        for (int t = 0; t < 8; ++t) {
            const float4 aw = *(const float4*)&s_att2[h2][t * 4];
            const uint2 p0 = *(const uint2*)&s_pairb[t * 4 + 0][c0];
            const uint2 p1 = *(const uint2*)&s_pairb[t * 4 + 1][c0];
            const uint2 p2 = *(const uint2*)&s_pairb[t * 4 + 2][c0];
            const uint2 p3 = *(const uint2*)&s_pairb[t * 4 + 3][c0];
            aA.x = fmaf(aw.x, bl16(p0.x), aA.x); aA.y = fmaf(aw.x, bh16(p0.x), aA.y);
            aA.z = fmaf(aw.x, bl16(p0.y), aA.z); aA.w = fmaf(aw.x, bh16(p0.y), aA.w);
            aB.x = fmaf(aw.y, bl16(p1.x), aB.x); aB.y = fmaf(aw.y, bh16(p1.x), aB.y);
            aB.z = fmaf(aw.y, bl16(p1.y), aB.z); aB.w = fmaf(aw.y, bh16(p1.y), aB.w);
            aA.x = fmaf(aw.z, bl16(p2.x), aA.x); aA.y = fmaf(aw.z, bh16(p2.x), aA.y);
            aA.z = fmaf(aw.z, bl16(p2.y), aA.z); aA.w = fmaf(aw.z, bh16(p2.y), aA.w);
            aB.x = fmaf(aw.w, bl16(p3.x), aB.x); aB.y = fmaf(aw.w, bh16(p3.x), aB.y);
            aB.z = fmaf(aw.w, bl16(p3.y), aB.z); aB.w = fmaf(aw.w, bh16(p3.y), aB.w);
        }
        ushort4 o;
        o.x = bf2u(aA.x + aB.x); o.y = bf2u(aA.y + aB.y);
        o.z = bf2u(aA.z + aB.z); o.w = bf2u(aA.w + aB.w);
        *(ushort4*)&cat[(size_t)i * DCAT + h2 * CPD + c0] = o;
    }

    // --- out_scalar tail: consume remaining v, reduce, store
    VACC(vA0, w1.x); VACC(vA1, w1.y);
    VACC(vB0, w1.z); VACC(vB1, w1.w);
#undef VLOAD
#undef VACC
    acc0 += __shfl_xor(acc0, 16); acc0 += __shfl_xor(acc0, 32);
    acc1 += __shfl_xor(acc1, 16); acc1 += __shfl_xor(acc1, 32);
    acc2 += __shfl_xor(acc2, 16); acc2 += __shfl_xor(acc2, 32);
    acc3 += __shfl_xor(acc3, 16); acc3 += __shfl_xor(acc3, 32);
    acc4 += __shfl_xor(acc4, 16); acc4 += __shfl_xor(acc4, 32);
    acc5 += __shfl_xor(acc5, 16); acc5 += __shfl_xor(acc5, 32);
    acc6 += __shfl_xor(acc6, 16); acc6 += __shfl_xor(acc6, 32);
    acc7 += __shfl_xor(acc7, 16); acc7 += __shfl_xor(acc7, 32);
    if (jg == 0) {
        short8 o;
        o[0] = (short)bf2u(acc0); o[1] = (short)bf2u(acc1);
        o[2] = (short)bf2u(acc2); o[3] = (short)bf2u(acc3);
        o[4] = (short)bf2u(acc4); o[5] = (short)bf2u(acc5);
        o[6] = (short)bf2u(acc6); o[7] = (short)bf2u(acc7);
        char* dst = (char*)cat + ((size_t)i * DCAT + NH * CPD) * 2 + slot * 16;
        *(short8*)dst = o;
    }
}

extern "C" void kernel_launch(void* const* d_in, const int* in_sizes, int n_in,
                              void* d_out, int out_size, void* d_ws, size_t ws_size,
                              hipStream_t stream)
{
    const float* local  = (const float*)d_in[0];
    const float* pair   = (const float*)d_in[1];
    const int*   nbr    = (const int*)d_in[2];
    const float* w_qkv  = (const float*)d_in[4];
    const float* g_q    = (const float*)d_in[5];
    const float* b_q    = (const float*)d_in[6];
    const float* g_k    = (const float*)d_in[7];
    const float* b_k    = (const float*)d_in[8];
    const float* w_bias = (const float*)d_in[9];
    const float* w_out  = (const float*)d_in[10];
    const float* b_out  = (const float*)d_in[11];
    float* out = (float*)d_out;

    char* base = (char*)d_ws;
    ushort*         qkvb  = (ushort*)base;                         // [N,1536] bf16
    __hip_bfloat16* cat_b = (__hip_bfloat16*)base;                 // aliases qkvb after LN
    ushort*         lc    = (ushort*)(base + 100663296u);
    __hip_bfloat16* wqkvT = (__hip_bfloat16*)(base + 117440512u);
    __hip_bfloat16* woutT = (__hip_bfloat16*)(base + 119013376u);
    __hip_bfloat16* qc    = (__hip_bfloat16*)(base + 120586240u);
    __hip_bfloat16* kc    = (__hip_bfloat16*)(base + 137363456u);
    __hip_bfloat16* vc    = (__hip_bfloat16*)(base + 154140672u);

    cvt_bf16_kernel<<<(NTOK * CDIM / 4 + 255) / 256, 256, 0, stream>>>(
        (const float4*)local, (ushort4*)lc, NTOK * CDIM / 4);
    transpose_cvt<<<dim3(QKV_W / 32, CDIM / 32), 256, 0, stream>>>(w_qkv, wqkvT, CDIM, QKV_W);
    transpose_cvt<<<dim3(CDIM / 32, DCAT / 32), 256, 0, stream>>>(w_out, woutT, DCAT, CDIM);

    // 1) qkv = local @ w_qkv  -> bf16 output
    hipLaunchKernelGGL((gemm_bf16<false, true>), dim3(QKV_W / 128, NTOK / 128), dim3(256), 0, stream,
                       lc, (const ushort*)wqkvT, nullptr, (void*)qkvb, NTOK, QKV_W, CDIM);

    // 2) LN(q), LN(k) from bf16 qkv -> compact bf16 q/k/v
    ln_kernel<<<NTOK * NH / 4, 256, 0, stream>>>(qkvb, g_q, b_q, g_k, b_k, qc, kc, vc);

    // 3) fused neighbour attention -> cat (bf16, aliases dead qkv buffer)
    attn_kernel<<<NTOK, 256, 0, stream>>>(qc, kc, vc, pair, nbr, w_bias, cat_b);

    // 4) out = cat @ w_out + b_out  (fp32 output)
    hipLaunchKernelGGL((gemm_bf16<true, false>), dim3(CDIM / 128, NTOK / 128), dim3(256), 0, stream,
                       (const ushort*)cat_b, (const ushort*)woutT, b_out, (void*)out, NTOK, CDIM, DCAT);
}

// Round 13
// 308.885 us; speedup vs baseline: 7.7751x; 1.0809x over previous
//
#include <hip/hip_runtime.h>
#include <hip/hip_bf16.h>
#include <cstdint>

#define NTOK 16384
#define CDIM 512
#define KNB 32
#define CPD 128
#define NH 8
#define SD 64
#define QKV_W 1536   // H*3*S
#define DCAT 1536    // H*CP + H*S

typedef __attribute__((ext_vector_type(8))) short short8;
typedef __attribute__((ext_vector_type(4))) float f32x4;

__device__ inline float bl16(unsigned w) { return __uint_as_float(w << 16); }
__device__ inline float bh16(unsigned w) { return __uint_as_float(w & 0xffff0000u); }

__device__ inline ushort bf2u(float x) {
    __hip_bfloat16 b = __float2bfloat16(x);
    return *(const ushort*)&b;
}

__device__ inline void gload_lds16(const void* g, void* l) {
    __builtin_amdgcn_global_load_lds((const __attribute__((address_space(1))) void*)g,
                                     (__attribute__((address_space(3))) void*)l, 16, 0, 0);
}

// ---------------- elementwise fp32 -> bf16 convert (vectorized) ----------------
__global__ __launch_bounds__(256) void cvt_bf16_kernel(const float4* __restrict__ in,
                                                       ushort4* __restrict__ out, int n4)
{
    const int idx = blockIdx.x * 256 + threadIdx.x;
    if (idx < n4) {
        const float4 v = in[idx];
        ushort4 o;
        o.x = bf2u(v.x); o.y = bf2u(v.y); o.z = bf2u(v.z); o.w = bf2u(v.w);
        out[idx] = o;
    }
}

// ---------------- transpose + convert: in [R][Cc] fp32 -> out [Cc][R] bf16 ----------------
__global__ __launch_bounds__(256) void transpose_cvt(const float* __restrict__ in,
                                                     __hip_bfloat16* __restrict__ out,
                                                     int R, int Cc)
{
    __shared__ float t[32][33];
    const int c0 = blockIdx.x * 32, r0 = blockIdx.y * 32;
    const int tx = threadIdx.x & 31, ty = threadIdx.x >> 5;
    #pragma unroll
    for (int rr = ty; rr < 32; rr += 8)
        t[rr][tx] = in[(size_t)(r0 + rr) * Cc + c0 + tx];
    __syncthreads();
    #pragma unroll
    for (int rr = ty; rr < 32; rr += 8)
        out[(size_t)(c0 + rr) * R + r0 + tx] = __float2bfloat16(t[tx][rr]);
}

// ---------------- bf16 MFMA GEMM with XCD-aware tile remap -------------------------------
// MODE 0: fp32 out + bias (GEMM2).  MODE 2: fused LayerNorm + q/k/v split (GEMM1):
// each wave's wc-half covers exactly one 64-col segment (seg = tileX*2+wc, typ=seg%3,
// h=seg/3); per-row mean/var via 4-step shfl_xor within the 16-lane lr group.
template<int MODE>
__global__ __launch_bounds__(256) void gemm_bf16(const ushort* __restrict__ A,
                                                 const ushort* __restrict__ Bt,
                                                 const float* __restrict__ bias,
                                                 void* __restrict__ Cv,
                                                 const float* __restrict__ g_q,
                                                 const float* __restrict__ b_q,
                                                 const float* __restrict__ g_k,
                                                 const float* __restrict__ b_k,
                                                 ushort* __restrict__ qc,
                                                 ushort* __restrict__ kc,
                                                 ushort* __restrict__ vc,
                                                 int M, int N, int K)
{
    __shared__ __align__(16) ushort Asl[128 * 32];
    __shared__ __align__(16) ushort Bsl[128 * 32];

    const int tid = threadIdx.x;
    const int wave = tid >> 6;
    const int lane = tid & 63;

    // --- XCD swizzle: consecutive linear blocks on one XCD share an A row-panel
    const int L = blockIdx.y * gridDim.x + blockIdx.x;
    const int xcd = L & 7;
    const int slot = L >> 3;
    const int ypx = gridDim.y >> 3;
    const int tileY = xcd * ypx + slot / gridDim.x;
    const int tileX = slot % gridDim.x;
    const int m0 = tileY * 128;
    const int n0 = tileX * 128;

    const int wr = wave >> 1, wc = wave & 1;

    f32x4 acc[4][4] = {};

    const int st_row_in_chunk = lane >> 2;
    const int st_bcol = (lane & 3) * 16;

    const int lr = lane & 15;
    const int kg = lane >> 4;

    for (int kt = 0; kt < K; kt += 32) {
        #pragma unroll
        for (int p = 0; p < 2; ++p) {
            const int chunk = wave * 2 + p;
            const int row = chunk * 16 + st_row_in_chunk;
            const char* asrc = (const char*)(A + (size_t)(m0 + row) * K + kt) + st_bcol;
            const char* bsrc = (const char*)(Bt + (size_t)(n0 + row) * K + kt) + st_bcol;
            gload_lds16(asrc, (char*)Asl + chunk * 1024);
            gload_lds16(bsrc, (char*)Bsl + chunk * 1024);
        }
        __syncthreads();

        short8 a[4], b[4];
        #pragma unroll
        for (int m = 0; m < 4; ++m)
            a[m] = *(const short8*)&Asl[(wr * 64 + m * 16 + lr) * 32 + kg * 8];
        #pragma unroll
        for (int n = 0; n < 4; ++n)
            b[n] = *(const short8*)&Bsl[(wc * 64 + n * 16 + lr) * 32 + kg * 8];
        #pragma unroll
        for (int m = 0; m < 4; ++m)
            #pragma unroll
            for (int n = 0; n < 4; ++n)
                acc[m][n] = __builtin_amdgcn_mfma_f32_16x16x32_bf16(a[m], b[n], acc[m][n], 0, 0, 0);
        __syncthreads();
    }

    if (MODE == 0) {
        #pragma unroll
        for (int m = 0; m < 4; ++m) {
            #pragma unroll
            for (int n = 0; n < 4; ++n) {
                const int col = n0 + wc * 64 + n * 16 + lr;
                const float bv = bias[col];
                #pragma unroll
                for (int r = 0; r < 4; ++r) {
                    const int row = m0 + wr * 64 + m * 16 + kg * 4 + r;
                    ((float*)Cv)[(size_t)row * N + col] = acc[m][n][r] + bv;
                }
            }
        }
    } else {
        // --- fused LayerNorm + split epilogue (GEMM1) ---
        const int seg = tileX * 2 + wc;   // 0..23
        const int typ = seg % 3;          // 0=q, 1=k, 2=v
        const int hh = seg / 3;
        float gv0 = 0.f, gv1 = 0.f, gv2 = 0.f, gv3 = 0.f;
        float bv0 = 0.f, bv1 = 0.f, bv2 = 0.f, bv3 = 0.f;
        if (typ < 2) {
            const float* g = typ == 0 ? g_q : g_k;
            const float* b = typ == 0 ? b_q : b_k;
            gv0 = g[lr]; gv1 = g[16 + lr]; gv2 = g[32 + lr]; gv3 = g[48 + lr];
            bv0 = b[lr]; bv1 = b[16 + lr]; bv2 = b[32 + lr]; bv3 = b[48 + lr];
        }
        ushort* dst0 = (typ == 0 ? qc : typ == 1 ? kc : vc);
        #pragma unroll
        for (int m = 0; m < 4; ++m) {
            #pragma unroll
            for (int r = 0; r < 4; ++r) {
                const int row = m0 + wr * 64 + m * 16 + kg * 4 + r;
                ushort* dst = dst0 + (size_t)row * 512 + hh * 64;
                const float x0 = acc[m][0][r], x1 = acc[m][1][r];
                const float x2 = acc[m][2][r], x3 = acc[m][3][r];
                if (typ == 2) {
                    dst[lr] = bf2u(x0); dst[16 + lr] = bf2u(x1);
                    dst[32 + lr] = bf2u(x2); dst[48 + lr] = bf2u(x3);
                } else {
                    float s = (x0 + x1) + (x2 + x3);
                    float s2 = fmaf(x0, x0, fmaf(x1, x1, fmaf(x2, x2, x3 * x3)));
                    s += __shfl_xor(s, 1);  s2 += __shfl_xor(s2, 1);
                    s += __shfl_xor(s, 2);  s2 += __shfl_xor(s2, 2);
                    s += __shfl_xor(s, 4);  s2 += __shfl_xor(s2, 4);
                    s += __shfl_xor(s, 8);  s2 += __shfl_xor(s2, 8);
                    const float mean = s * (1.0f / 64.0f);
                    const float var = s2 * (1.0f / 64.0f) - mean * mean;
                    const float inv = rsqrtf(var + 1e-5f);
                    dst[lr]      = bf2u((x0 - mean) * inv * gv0 + bv0);
                    dst[16 + lr] = bf2u((x1 - mean) * inv * gv1 + bv1);
                    dst[32 + lr] = bf2u((x2 - mean) * inv * gv2 + bv2);
                    dst[48 + lr] = bf2u((x3 - mean) * inv * gv3 + bv3);
                }
            }
        }
    }
}

// ---------------- fused neighbour attention: one block per token i ----------------
__global__ __launch_bounds__(256) void attn_kernel(const __hip_bfloat16* __restrict__ qc,
                                                   const __hip_bfloat16* __restrict__ kc,
                                                   const __hip_bfloat16* __restrict__ vc,
                                                   const float* __restrict__ pair,
                                                   const int* __restrict__ nbr,
                                                   const float* __restrict__ w_bias,
                                                   __hip_bfloat16* __restrict__ cat)
{
    __shared__ __align__(16) ushort s_pairb[KNB][CPD + 8];  // 8.5 KB, row 272 B
    __shared__ __align__(16) ushort s_wbTb[NH][CPD + 8];    // 2.2 KB
    __shared__ __align__(16) ushort s_qb[NH][SD + 8];       // 1.2 KB
    __shared__ __align__(16) float s_att[NH][KNB + 4];      // bias -> logits (in place)
    __shared__ __align__(16) float s_att2[NH][KNB + 4];     // softmax weights
    __shared__ int s_nb[KNB];

    const int i = blockIdx.x;
    const int tid = threadIdx.x;
    const int j = tid >> 3;
    const int h = tid & 7;
    const int wave = tid >> 6;
    const int lane = tid & 63;

    // --- k-gather 2-deep pipeline, phase 0 issued pre-barrier (16 regs peak)
    const int rowj = nbr[i * KNB + j];
    const int rk = rowj < 0 ? 0 : rowj;
    const uint4* kp = (const uint4*)(kc + ((size_t)rk * NH + h) * SD);
    uint4 kA0 = kp[0], kA1 = kp[1];

    // --- LDS staging
    if (tid < KNB) s_nb[tid] = nbr[i * KNB + tid];
    if (tid < 64) {   // q already bf16: straight uint4 copy
        const uint4 qw = ((const uint4*)(qc + (size_t)i * 512))[tid];
        *(uint4*)&s_qb[tid >> 3][(tid & 7) * 8] = qw;
    }
    {   // w_bias [128][8] fp32 -> s_wbTb[h][c] bf16
        const float4 w4 = ((const float4*)w_bias)[tid];
        const int c = tid >> 1;
        const int h0 = (tid & 1) * 4;
        s_wbTb[h0 + 0][c] = bf2u(w4.x);
        s_wbTb[h0 + 1][c] = bf2u(w4.y);
        s_wbTb[h0 + 2][c] = bf2u(w4.z);
        s_wbTb[h0 + 3][c] = bf2u(w4.w);
    }
    {   // pair tile fp32 -> bf16 LDS; NONTEMPORAL: pair is single-use
        const f32x4* pr = (const f32x4*)(pair + (size_t)i * KNB * CPD);
        #pragma unroll
        for (int t2 = 0; t2 < 2; ++t2) {
            const int ch = t2 * 256 + tid;
            const int row = ch >> 4;
            const int c8 = (ch & 15) * 8;
            const f32x4 a = __builtin_nontemporal_load(pr + row * 32 + (c8 >> 2));
            const f32x4 b = __builtin_nontemporal_load(pr + row * 32 + (c8 >> 2) + 1);
            short8 o;
            o[0] = (short)bf2u(a[0]); o[1] = (short)bf2u(a[1]);
            o[2] = (short)bf2u(a[2]); o[3] = (short)bf2u(a[3]);
            o[4] = (short)bf2u(b[0]); o[5] = (short)bf2u(b[1]);
            o[6] = (short)bf2u(b[2]); o[7] = (short)bf2u(b[3]);
            *(short8*)&s_pairb[row][c8] = o;
        }
    }
    __syncthreads();

    const uint4* qrow = (const uint4*)&s_qb[h][0];
    float d0 = 0.f, d1 = 0.f, d2 = 0.f, d3 = 0.f;

#define DOT_CHUNK(KV, u) do { \
        const uint4 Q = qrow[u]; \
        d0 = fmaf(bl16(KV.x), bl16(Q.x), fmaf(bh16(KV.x), bh16(Q.x), d0)); \
        d1 = fmaf(bl16(KV.y), bl16(Q.y), fmaf(bh16(KV.y), bh16(Q.y), d1)); \
        d2 = fmaf(bl16(KV.z), bl16(Q.z), fmaf(bh16(KV.z), bh16(Q.z), d2)); \
        d3 = fmaf(bl16(KV.w), bl16(Q.w), fmaf(bh16(KV.w), bh16(Q.w), d3)); \
    } while (0)

    uint4 kB0 = kp[2], kB1 = kp[3];
    asm volatile("" ::: "memory");
    DOT_CHUNK(kA0, 0); DOT_CHUNK(kA1, 1);
    kA0 = kp[4]; kA1 = kp[5];
    asm volatile("" ::: "memory");

    // --- waves 0,1: bias = P @ Wb via MFMA (covers kA latency)
    if (wave < 2) {
        const int lr = lane & 15;
        const int kg = lane >> 4;
        f32x4 cacc = {};
        const ushort* arow = &s_pairb[wave * 16 + lr][kg * 8];
        const ushort* brow = &s_wbTb[lr & 7][kg * 8];   // cols n>=8 read aliased rows, discarded
        #pragma unroll
        for (int ks = 0; ks < 4; ++ks) {
            const short8 af = *(const short8*)(arow + ks * 32);
            const short8 bf = *(const short8*)(brow + ks * 32);
            cacc = __builtin_amdgcn_mfma_f32_16x16x32_bf16(af, bf, cacc, 0, 0, 0);
        }
        if (lr < 8) {   // C: col h = lr, row j = wave*16 + kg*4 + r
            const int jj = wave * 16 + kg * 4;
            s_att[lr][jj + 0] = cacc[0];
            s_att[lr][jj + 1] = cacc[1];
            s_att[lr][jj + 2] = cacc[2];
            s_att[lr][jj + 3] = cacc[3];
        }
    }

    DOT_CHUNK(kB0, 2); DOT_CHUNK(kB1, 3);
    kB0 = kp[6]; kB1 = kp[7];
    asm volatile("" ::: "memory");
    DOT_CHUNK(kA0, 4); DOT_CHUNK(kA1, 5);
    DOT_CHUNK(kB0, 6); DOT_CHUNK(kB1, 7);
#undef DOT_CHUNK
    __syncthreads();   // MFMA bias in s_att visible to all

    // --- logit = w_L*(dot/8 + bias); in-place update of s_att[h][j]
    float logit = -1e9f;
    if (rowj >= 0) {
        const float dot = (d0 + d1) + (d2 + d3);
        logit = 0.70710678118f * (dot * 0.125f + s_att[h][j]);
    }
    s_att[h][j] = logit;
    __syncthreads();

    // --- out_scalar mapping + v-gather 2-deep pipeline (phase 0 covers softmax)
    const int slot = wave * 16 + (lane & 15);   // h = slot>>3, 16B chunk = slot&7
    const int jg = lane >> 4;                   // owns rows jg*8 .. jg*8+7
    const int hh = slot >> 3;
    const char* vbase = (const char*)vc;

#define VLOAD(u) (*(const uint4*)(vbase + (size_t)(s_nb[jg * 8 + (u)] < 0 ? 0 : s_nb[jg * 8 + (u)]) * 1024 + slot * 16))
#define VACC(V, a) do { \
        acc0 = fmaf(a, bl16(V.x), acc0); acc1 = fmaf(a, bh16(V.x), acc1); \
        acc2 = fmaf(a, bl16(V.y), acc2); acc3 = fmaf(a, bh16(V.y), acc3); \
        acc4 = fmaf(a, bl16(V.z), acc4); acc5 = fmaf(a, bh16(V.z), acc5); \
        acc6 = fmaf(a, bl16(V.w), acc6); acc7 = fmaf(a, bh16(V.w), acc7); \
    } while (0)

    uint4 vA0 = VLOAD(0), vA1 = VLOAD(1);
    asm volatile("" ::: "memory");

    // --- softmax over j: two register-lean float4 passes over s_att[h][*]
    {
        float mx = -1e30f;
        #pragma unroll
        for (int t = 0; t < 8; ++t) {
            const float4 w = *(const float4*)&s_att[h][t * 4];
            mx = fmaxf(mx, fmaxf(fmaxf(w.x, w.y), fmaxf(w.z, w.w)));
        }
        float s0 = 0.f, s1 = 0.f;
        #pragma unroll
        for (int t = 0; t < 8; ++t) {
            const float4 w = *(const float4*)&s_att[h][t * 4];
            s0 += __expf(w.x - mx) + __expf(w.z - mx);
            s1 += __expf(w.y - mx) + __expf(w.w - mx);
        }
        float aval = __expf(logit - mx) / (s0 + s1);
        if (rowj < 0) aval = 0.0f;
        s_att2[h][j] = aval;
    }
    __syncthreads();

    // --- att weights for out_scalar (float4 broadcast reads)
    const float4 w0 = *(const float4*)&s_att2[hh][jg * 8];
    const float4 w1 = *(const float4*)&s_att2[hh][jg * 8 + 4];

    float acc0 = 0.f, acc1 = 0.f, acc2 = 0.f, acc3 = 0.f;
    float acc4 = 0.f, acc5 = 0.f, acc6 = 0.f, acc7 = 0.f;

    uint4 vB0 = VLOAD(2), vB1 = VLOAD(3);
    asm volatile("" ::: "memory");
    VACC(vA0, w0.x); VACC(vA1, w0.y);
    vA0 = VLOAD(4); vA1 = VLOAD(5);
    asm volatile("" ::: "memory");
    VACC(vB0, w0.z); VACC(vB1, w0.w);
    vB0 = VLOAD(6); vB1 = VLOAD(7);
    asm volatile("" ::: "memory");

    // --- out_pair[h,c] -> cat[i, h*128+c]; covers the vA/vB latency
    {
        const int h2 = tid >> 5;
        const int c0 = (tid & 31) * 4;
        float4 aA = make_float4(0.f, 0.f, 0.f, 0.f);
        float4 aB = make_float4(0.f, 0.f, 0.f, 0.f);
        #pragma unroll
        for (int t = 0; t < 8; ++t) {
            const float4 aw = *(const float4*)&s_att2[h2][t * 4];
            const uint2 p0 = *(const uint2*)&s_pairb[t * 4 + 0][c0];
            const uint2 p1 = *(const uint2*)&s_pairb[t * 4 + 1][c0];
            const uint2 p2 = *(const uint2*)&s_pairb[t * 4 + 2][c0];
            const uint2 p3 = *(const uint2*)&s_pairb[t * 4 + 3][c0];
            aA.x = fmaf(aw.x, bl16(p0.x), aA.x); aA.y = fmaf(aw.x, bh16(p0.x), aA.y);
            aA.z = fmaf(aw.x, bl16(p0.y), aA.z); aA.w = fmaf(aw.x, bh16(p0.y), aA.w);
            aB.x = fmaf(aw.y, bl16(p1.x), aB.x); aB.y = fmaf(aw.y, bh16(p1.x), aB.y);
            aB.z = fmaf(aw.y, bl16(p1.y), aB.z); aB.w = fmaf(aw.y, bh16(p1.y), aB.w);
            aA.x = fmaf(aw.z, bl16(p2.x), aA.x); aA.y = fmaf(aw.z, bh16(p2.x), aA.y);
            aA.z = fmaf(aw.z, bl16(p2.y), aA.z); aA.w = fmaf(aw.z, bh16(p2.y), aA.w);
            aB.x = fmaf(aw.w, bl16(p3.x), aB.x); aB.y = fmaf(aw.w, bh16(p3.x), aB.y);
            aB.z = fmaf(aw.w, bl16(p3.y), aB.z); aB.w = fmaf(aw.w, bh16(p3.y), aB.w);
        }
        ushort4 o;
        o.x = bf2u(aA.x + aB.x); o.y = bf2u(aA.y + aB.y);
        o.z = bf2u(aA.z + aB.z); o.w = bf2u(aA.w + aB.w);
        *(ushort4*)&cat[(size_t)i * DCAT + h2 * CPD + c0] = o;
    }

    // --- out_scalar tail: consume remaining v, reduce, store
    VACC(vA0, w1.x); VACC(vA1, w1.y);
    VACC(vB0, w1.z); VACC(vB1, w1.w);
#undef VLOAD
#undef VACC
    acc0 += __shfl_xor(acc0, 16); acc0 += __shfl_xor(acc0, 32);
    acc1 += __shfl_xor(acc1, 16); acc1 += __shfl_xor(acc1, 32);
    acc2 += __shfl_xor(acc2, 16); acc2 += __shfl_xor(acc2, 32);
    acc3 += __shfl_xor(acc3, 16); acc3 += __shfl_xor(acc3, 32);
    acc4 += __shfl_xor(acc4, 16); acc4 += __shfl_xor(acc4, 32);
    acc5 += __shfl_xor(acc5, 16); acc5 += __shfl_xor(acc5, 32);
    acc6 += __shfl_xor(acc6, 16); acc6 += __shfl_xor(acc6, 32);
    acc7 += __shfl_xor(acc7, 16); acc7 += __shfl_xor(acc7, 32);
    if (jg == 0) {
        short8 o;
        o[0] = (short)bf2u(acc0); o[1] = (short)bf2u(acc1);
        o[2] = (short)bf2u(acc2); o[3] = (short)bf2u(acc3);
        o[4] = (short)bf2u(acc4); o[5] = (short)bf2u(acc5);
        o[6] = (short)bf2u(acc6); o[7] = (short)bf2u(acc7);
        char* dst = (char*)cat + ((size_t)i * DCAT + NH * CPD) * 2 + slot * 16;
        *(short8*)dst = o;
    }
}

extern "C" void kernel_launch(void* const* d_in, const int* in_sizes, int n_in,
                              void* d_out, int out_size, void* d_ws, size_t ws_size,
                              hipStream_t stream)
{
    const float* local  = (const float*)d_in[0];
    const float* pair   = (const float*)d_in[1];
    const int*   nbr    = (const int*)d_in[2];
    const float* w_qkv  = (const float*)d_in[4];
    const float* g_q    = (const float*)d_in[5];
    const float* b_q    = (const float*)d_in[6];
    const float* g_k    = (const float*)d_in[7];
    const float* b_k    = (const float*)d_in[8];
    const float* w_bias = (const float*)d_in[9];
    const float* w_out  = (const float*)d_in[10];
    const float* b_out  = (const float*)d_in[11];
    float* out = (float*)d_out;

    char* base = (char*)d_ws;
    __hip_bfloat16* cat_b = (__hip_bfloat16*)base;                 // [N,1536] bf16
    ushort*         lc    = (ushort*)(base + 100663296u);
    __hip_bfloat16* wqkvT = (__hip_bfloat16*)(base + 117440512u);
    __hip_bfloat16* woutT = (__hip_bfloat16*)(base + 119013376u);
    __hip_bfloat16* qc    = (__hip_bfloat16*)(base + 120586240u);
    __hip_bfloat16* kc    = (__hip_bfloat16*)(base + 137363456u);
    __hip_bfloat16* vc    = (__hip_bfloat16*)(base + 154140672u);

    cvt_bf16_kernel<<<(NTOK * CDIM / 4 + 255) / 256, 256, 0, stream>>>(
        (const float4*)local, (ushort4*)lc, NTOK * CDIM / 4);
    transpose_cvt<<<dim3(QKV_W / 32, CDIM / 32), 256, 0, stream>>>(w_qkv, wqkvT, CDIM, QKV_W);
    transpose_cvt<<<dim3(CDIM / 32, DCAT / 32), 256, 0, stream>>>(w_out, woutT, DCAT, CDIM);

    // 1) qkv = local @ w_qkv with fused LayerNorm + q/k/v split -> qc,kc,vc (bf16 compact)
    hipLaunchKernelGGL((gemm_bf16<2>), dim3(QKV_W / 128, NTOK / 128), dim3(256), 0, stream,
                       lc, (const ushort*)wqkvT, nullptr, nullptr,
                       g_q, b_q, g_k, b_k,
                       (ushort*)qc, (ushort*)kc, (ushort*)vc, NTOK, QKV_W, CDIM);

    // 2) fused neighbour attention -> cat (bf16)
    attn_kernel<<<NTOK, 256, 0, stream>>>(qc, kc, vc, pair, nbr, w_bias, cat_b);

    // 3) out = cat @ w_out + b_out  (fp32 output)
    hipLaunchKernelGGL((gemm_bf16<0>), dim3(CDIM / 128, NTOK / 128), dim3(256), 0, stream,
                       (const ushort*)cat_b, (const ushort*)woutT, b_out, (void*)out,
                       nullptr, nullptr, nullptr, nullptr,
                       nullptr, nullptr, nullptr, NTOK, CDIM, DCAT);
}